// Round 1
// baseline (557.035 us; speedup 1.0000x reference)
//
#include <hip/hip_runtime.h>
#include <stdint.h>
#include <math.h>

typedef float f32x4 __attribute__((ext_vector_type(4)));
typedef short s16x8 __attribute__((ext_vector_type(8)));
typedef unsigned short bfu;

#define AS1q const __attribute__((address_space(1))) void*
#define AS3q __attribute__((address_space(3))) void*

static __device__ __forceinline__ float bf2f(bfu v) {
  return __uint_as_float(((unsigned int)v) << 16);
}
static __device__ __forceinline__ bfu f2bf(float f) {
  unsigned int u = __float_as_uint(f);
  return (bfu)((u + 0x7fffu + ((u >> 16) & 1u)) >> 16);
}

// ---------------- weight convert + transpose: W[K][N] f32 -> Wt[N][K] bf16 ----------------
__global__ __launch_bounds__(256) void wconv_t(const float* __restrict__ W, bfu* __restrict__ Wt,
                                               int K, int N) {
  __shared__ float t[32][33];
  int tx = threadIdx.x & 31, ty = threadIdx.x >> 5;
  int nb = blockIdx.x * 32, kb = blockIdx.y * 32;
#pragma unroll
  for (int i = 0; i < 4; i++) {
    int r = ty + i * 8;
    t[r][tx] = W[(size_t)(kb + r) * N + nb + tx];
  }
  __syncthreads();
#pragma unroll
  for (int i = 0; i < 4; i++) {
    int r = ty + i * 8;
    Wt[(size_t)(nb + r) * K + kb + tx] = f2bf(t[tx][r]);
  }
}

// ---------------- rope tables (bf16-rounded, matches reference) ----------------
__global__ void rope_tab(bfu* __restrict__ ct, bfu* __restrict__ st) {
  int idx = blockIdx.x * 256 + threadIdx.x;  // 1024*32
  int s = idx >> 5, i = idx & 31;
  float f = powf(1000.0f, -(float)i / 32.0f);
  float fr = (float)s * f;
  ct[idx] = f2bf(cosf(fr));
  st[idx] = f2bf(sinf(fr));
}

// ---------------- rmsnorm: h[4096][1024] f32 -> inner bf16 ----------------
__global__ __launch_bounds__(256) void rmsnorm_k(const float* __restrict__ h, bfu* __restrict__ inner) {
  int row = blockIdx.x;
  const float* hr = h + (size_t)row * 1024;
  f32x4 x = *reinterpret_cast<const f32x4*>(hr + threadIdx.x * 4);
  float ss = x[0] * x[0] + x[1] * x[1] + x[2] * x[2] + x[3] * x[3];
  for (int off = 32; off; off >>= 1) ss += __shfl_down(ss, off);
  __shared__ float wsum[4];
  int wave = threadIdx.x >> 6, lane = threadIdx.x & 63;
  if (lane == 0) wsum[wave] = ss;
  __syncthreads();
  float tot = wsum[0] + wsum[1] + wsum[2] + wsum[3];
  float r = rsqrtf(tot * (1.0f / 1024.0f) + 1.1920929e-07f);
  bfu* o = inner + (size_t)row * 1024 + threadIdx.x * 4;
  o[0] = f2bf(x[0] * r); o[1] = f2bf(x[1] * r);
  o[2] = f2bf(x[2] * r); o[3] = f2bf(x[3] * r);
}

// ---------------- GEMM: C[M][N] = A[M][K](bf16) * Bt[N][K](bf16)^T  (m97 structure) ----------------
// EPI 0: outF = acc            EPI 1: outF += acc + bias[col]
// EPI 2: outB = bf16(acc+bias) EPI 3: outF = acc + bias[col] + lam*hres
template <int EPI>
__global__ __launch_bounds__(256) void gemm_bt(const bfu* __restrict__ A, const bfu* __restrict__ Bt,
                                               float* __restrict__ outF, bfu* __restrict__ outB,
                                               const float* __restrict__ bias,
                                               const float* __restrict__ hres,
                                               const float* __restrict__ lam,
                                               int M, int N, int K) {
  __shared__ __align__(16) char lds[32768];  // 2 bufs x (A 8KB | B 8KB)
  int nbx = N >> 7;
  int nwg = gridDim.x;
  int id = blockIdx.x;
  if ((nwg & 7) == 0) { int q = nwg >> 3; id = (id & 7) * q + (id >> 3); }  // XCD swizzle
  int bm = id / nbx, bn = id % nbx;
  int tid = threadIdx.x, wave = tid >> 6, lane = tid & 63;
  int wr = wave >> 1, wc = wave & 1;
  int g = lane >> 4, l15 = lane & 15;

  f32x4 acc[4][4];
#pragma unroll
  for (int m = 0; m < 4; m++)
#pragma unroll
    for (int n = 0; n < 4; n++) acc[m][n] = (f32x4){0.f, 0.f, 0.f, 0.f};

  auto stage = [&](int buf, int t) {
    int k0 = t << 5;
#pragma unroll
    for (int i = 0; i < 2; i++) {
      int row = (tid >> 2) + (i << 6);
      int sk = k0 + (((tid & 3) ^ (row & 3)) << 3);
      const bfu* ga = A + (size_t)(bm * 128 + row) * K + sk;
      char* la = lds + buf * 16384 + i * 4096 + wave * 1024;
      __builtin_amdgcn_global_load_lds((AS1q)ga, (AS3q)la, 16, 0, 0);
      const bfu* gb = Bt + (size_t)(bn * 128 + row) * K + sk;
      char* lb = lds + buf * 16384 + 8192 + i * 4096 + wave * 1024;
      __builtin_amdgcn_global_load_lds((AS1q)gb, (AS3q)lb, 16, 0, 0);
    }
  };

  int nt = K >> 5;
  stage(0, 0);
  __syncthreads();
  int cur = 0;
  for (int t = 0; t < nt; t++) {
    if (t + 1 < nt) stage(cur ^ 1, t + 1);
    const char* la = lds + cur * 16384;
    const char* lb = la + 8192;
    s16x8 af[4], bfr[4];
#pragma unroll
    for (int m = 0; m < 4; m++) {
      int row = wr * 64 + m * 16 + l15;
      af[m] = *reinterpret_cast<const s16x8*>(la + row * 64 + ((g ^ (row & 3)) << 4));
    }
#pragma unroll
    for (int n = 0; n < 4; n++) {
      int row = wc * 64 + n * 16 + l15;
      bfr[n] = *reinterpret_cast<const s16x8*>(lb + row * 64 + ((g ^ (row & 3)) << 4));
    }
#pragma unroll
    for (int m = 0; m < 4; m++)
#pragma unroll
      for (int n = 0; n < 4; n++)
        acc[m][n] = __builtin_amdgcn_mfma_f32_16x16x32_bf16(af[m], bfr[n], acc[m][n], 0, 0, 0);
    __syncthreads();
    cur ^= 1;
  }

  float lv = (EPI == 3) ? lam[0] : 0.0f;
#pragma unroll
  for (int m = 0; m < 4; m++) {
    int row = bm * 128 + wr * 64 + m * 16 + g * 4;
#pragma unroll
    for (int n = 0; n < 4; n++) {
      int col = bn * 128 + wc * 64 + n * 16 + l15;
#pragma unroll
      for (int r = 0; r < 4; r++) {
        float v = acc[m][n][r];
        size_t o = (size_t)(row + r) * N + col;
        if (EPI == 0) outF[o] = v;
        else if (EPI == 1) outF[o] += v + bias[col];
        else if (EPI == 2) outB[o] = f2bf(v + bias[col]);
        else outF[o] = v + bias[col] + lv * hres[o];
      }
    }
  }
}

// ---------------- l2norm + rope ----------------
// raw: f32, stride 5120, row index = (b*S+s), col = h*64+d (pointer pre-offset to projection block)
// out layout [bh][s][d]; OUTBF: bf16 (q,k) else f32 (bq,bk)
template <bool OUTBF>
__global__ __launch_bounds__(256) void ropenorm(const float* __restrict__ raw,
                                                const bfu* __restrict__ ct, const bfu* __restrict__ st,
                                                float* __restrict__ of, bfu* __restrict__ ob) {
  int wave = threadIdx.x >> 6, lane = threadIdx.x & 63;
  int idx = blockIdx.x * 4 + wave;  // (b*S+s)*16 + h, total 65536
  int h = idx & 15;
  int s = (idx >> 4) & 1023;
  int b = idx >> 14;
  size_t rowi = (size_t)(idx >> 4);
  float x = raw[rowi * 5120 + (h << 6) + lane];
  float ss = x * x;
#pragma unroll
  for (int m = 1; m < 64; m <<= 1) ss += __shfl_xor(ss, m);
  float nrm = sqrtf(ss);
  float xn = x / fmaxf(nrm, 1e-12f);
  float part = __shfl_xor(xn, 32);
  int pi = lane & 31;
  float c = bf2f(ct[(s << 5) + pi]);
  float sn = bf2f(st[(s << 5) + pi]);
  float outv = (lane < 32) ? (xn * c + part * sn) : (xn * c - part * sn);
  size_t dofs = ((size_t)((b << 4) + h) * 1024 + s) * 64 + lane;
  if (OUTBF) ob[dofs] = f2bf(outv);
  else of[dofs] = outv;
}

// ---------------- v transpose: raw v (f32 stride 5120) -> vT bf16 [bh][d][s] ----------------
__global__ __launch_bounds__(256) void vtrans(const float* __restrict__ raw, bfu* __restrict__ vT) {
  __shared__ float t[64][65];
  int bh = blockIdx.y, stile = blockIdx.x;
  int b = bh >> 4, h = bh & 15;
  int s0 = stile << 6;
  for (int ii = threadIdx.x; ii < 4096; ii += 256) {
    int r = ii >> 6, d = ii & 63;
    t[r][d] = raw[(size_t)(b * 1024 + s0 + r) * 5120 + (h << 6) + d];
  }
  __syncthreads();
  for (int ii = threadIdx.x; ii < 4096; ii += 256) {
    int d = ii >> 6, sc = ii & 63;
    vT[((size_t)(bh * 64 + d) << 10) + s0 + sc] = f2bf(t[sc][d]);
  }
}

// ---------------- brow = scale * bq_i . prefix(bk)_i  (chunked prefix) ----------------
__global__ void bk_chunksum(const float* __restrict__ bk, float* __restrict__ csum) {
  int cid = blockIdx.x;  // bh*8 + c
  int bh = cid >> 3, c = cid & 7, lane = threadIdx.x;
  float s = 0.f;
  const float* p = bk + ((size_t)bh * 1024 + c * 128) * 64 + lane;
  for (int j = 0; j < 128; j++) s += p[(size_t)j * 64];
  csum[cid * 64 + lane] = s;
}

__global__ void brow_k(const float* __restrict__ bq, const float* __restrict__ bk,
                       const float* __restrict__ csum, float* __restrict__ brow) {
  int cid = blockIdx.x;
  int bh = cid >> 3, c = cid & 7, lane = threadIdx.x;
  float p = 0.f;
  for (int cc = 0; cc < c; cc++) p += csum[(bh * 8 + cc) * 64 + lane];
  size_t base = ((size_t)bh * 1024 + c * 128) * 64 + lane;
  for (int j = 0; j < 128; j++) {
    p += bk[base + (size_t)j * 64];
    float t = bq[base + (size_t)j * 64] * p;
#pragma unroll
    for (int m2 = 1; m2 < 64; m2 <<= 1) t += __shfl_xor(t, m2);
    if (lane == 0) brow[bh * 1024 + c * 128 + j] = 0.125f * t;
  }
}

// ---------------- flash attention: y = l2ns * softmax(qk^T, causal) @ v + brow ----------------
__global__ __launch_bounds__(256) void flash_k(const bfu* __restrict__ q, const bfu* __restrict__ k,
                                               const bfu* __restrict__ vT,
                                               const float* __restrict__ brow,
                                               const float* __restrict__ l2p,
                                               bfu* __restrict__ y) {
  __shared__ __align__(16) bfu P[4][16][80];
  int qt = blockIdx.x, bh = blockIdx.y;
  int wave = threadIdx.x >> 6, lane = threadIdx.x & 63;
  int g = lane >> 4, l15 = lane & 15;
  int irow = qt * 64 + wave * 16;
  const size_t bhofs = (size_t)bh << 16;

  s16x8 aq[2];
#pragma unroll
  for (int ks = 0; ks < 2; ks++)
    aq[ks] = *reinterpret_cast<const s16x8*>(q + bhofs + (size_t)(irow + l15) * 64 + ks * 32 + g * 8);

  f32x4 O[4];
  float mr[4], lr[4];
#pragma unroll
  for (int r = 0; r < 4; r++) { O[r] = (f32x4){0.f, 0.f, 0.f, 0.f}; mr[r] = -3.0e38f; lr[r] = 0.f; }

  for (int jt = 0; jt <= qt; jt++) {
    f32x4 sfr[4];
#pragma unroll
    for (int nt = 0; nt < 4; nt++) sfr[nt] = (f32x4){0.f, 0.f, 0.f, 0.f};
#pragma unroll
    for (int nt = 0; nt < 4; nt++) {
#pragma unroll
      for (int ks = 0; ks < 2; ks++) {
        s16x8 bk_ = *reinterpret_cast<const s16x8*>(
            k + bhofs + (size_t)(jt * 64 + nt * 16 + l15) * 64 + ks * 32 + g * 8);
        sfr[nt] = __builtin_amdgcn_mfma_f32_16x16x32_bf16(aq[ks], bk_, sfr[nt], 0, 0, 0);
      }
    }
    if (jt == qt) {
#pragma unroll
      for (int nt = 0; nt < 4; nt++)
#pragma unroll
        for (int r = 0; r < 4; r++) {
          int col = nt * 16 + l15;
          int rr = wave * 16 + g * 4 + r;
          if (col > rr) sfr[nt][r] = -1e30f;
        }
    }
    float alpha[4];
#pragma unroll
    for (int r = 0; r < 4; r++) {
      float v = fmaxf(fmaxf(sfr[0][r], sfr[1][r]), fmaxf(sfr[2][r], sfr[3][r]));
#pragma unroll
      for (int m2 = 1; m2 < 16; m2 <<= 1) v = fmaxf(v, __shfl_xor(v, m2));
      float mn = fmaxf(mr[r], v);
      alpha[r] = __expf(mr[r] - mn);
      mr[r] = mn;
    }
    float pv[4][4];
#pragma unroll
    for (int nt = 0; nt < 4; nt++)
#pragma unroll
      for (int r = 0; r < 4; r++) pv[nt][r] = __expf(sfr[nt][r] - mr[r]);
#pragma unroll
    for (int r = 0; r < 4; r++) {
      float v = pv[0][r] + pv[1][r] + pv[2][r] + pv[3][r];
#pragma unroll
      for (int m2 = 1; m2 < 16; m2 <<= 1) v += __shfl_xor(v, m2);
      lr[r] = lr[r] * alpha[r] + v;
    }
#pragma unroll
    for (int nt = 0; nt < 4; nt++)
#pragma unroll
      for (int r = 0; r < 4; r++) {
        O[nt][r] *= alpha[r];
        P[wave][g * 4 + r][nt * 16 + l15] = f2bf(pv[nt][r]);
      }
    asm volatile("s_waitcnt lgkmcnt(0)" ::: "memory");
    __builtin_amdgcn_sched_barrier(0);
    s16x8 pa[2];
#pragma unroll
    for (int ks = 0; ks < 2; ks++)
      pa[ks] = *reinterpret_cast<const s16x8*>(&P[wave][l15][ks * 32 + g * 8]);
#pragma unroll
    for (int nt = 0; nt < 4; nt++) {
#pragma unroll
      for (int ks = 0; ks < 2; ks++) {
        s16x8 bv = *reinterpret_cast<const s16x8*>(
            vT + ((size_t)(bh * 64 + nt * 16 + l15) << 10) + jt * 64 + ks * 32 + g * 8);
        O[nt] = __builtin_amdgcn_mfma_f32_16x16x32_bf16(pa[ks], bv, O[nt], 0, 0, 0);
      }
    }
  }

  float l2ns = l2p[0];
  int b = bh >> 4, h = bh & 15;
#pragma unroll
  for (int nt = 0; nt < 4; nt++)
#pragma unroll
    for (int r = 0; r < 4; r++) {
      int rowg = qt * 64 + wave * 16 + g * 4 + r;
      float val = O[nt][r] * (l2ns / lr[r]) + brow[bh * 1024 + rowg];
      y[((size_t)(b * 1024 + rowg) << 10) + h * 64 + nt * 16 + l15] = f2bf(val);
    }
}

// ---------------- silu(gate)*xh ----------------
__global__ __launch_bounds__(256) void silu_k(const bfu* __restrict__ u, bfu* __restrict__ act) {
  int t = blockIdx.x * 256 + threadIdx.x;
  int row = t >> 9, cp = (t & 511) << 3;
  s16x8 xh = *reinterpret_cast<const s16x8*>(u + ((size_t)row << 13) + cp);
  s16x8 gt = *reinterpret_cast<const s16x8*>(u + ((size_t)row << 13) + 4096 + cp);
  s16x8 o;
#pragma unroll
  for (int j = 0; j < 8; j++) {
    float gv = bf2f((bfu)gt[j]);
    float xv = bf2f((bfu)xh[j]);
    float a = gv / (1.0f + __expf(-gv)) * xv;
    o[j] = (short)f2bf(a);
  }
  *reinterpret_cast<s16x8*>(act + ((size_t)row << 12) + cp) = o;
}

// ================= host =================
extern "C" void kernel_launch(void* const* d_in, const int* in_sizes, int n_in,
                              void* d_out, int out_size, void* d_ws, size_t ws_size,
                              hipStream_t stream) {
  const float* h      = (const float*)d_in[0];
  const float* Wq     = (const float*)d_in[2];
  const float* Wk     = (const float*)d_in[3];
  const float* Wv     = (const float*)d_in[4];
  const float* WqB    = (const float*)d_in[5];
  const float* WkB    = (const float*)d_in[6];
  const float* Wo     = (const float*)d_in[7];
  const float* bo     = (const float*)d_in[8];
  const float* Wffin  = (const float*)d_in[9];
  const float* bffin  = (const float*)d_in[10];
  const float* Wffout = (const float*)d_in[11];
  const float* bffout = (const float*)d_in[12];
  const float* lam    = (const float*)d_in[13];
  const float* l2ns   = (const float*)d_in[14];
  float* out = (float*)d_out;

  char* ws = (char*)d_ws;
  size_t off = 0;
  auto alloc = [&](size_t bytes) { void* p = ws + off; off += bytes; return p; };
  bfu* wt5   = (bfu*)alloc(5ull * 1024 * 1024 * 2);   // Wq..WkB transposed, contiguous [5120][1024]
  bfu* wto   = (bfu*)alloc(1ull * 1024 * 1024 * 2);
  bfu* wtfi  = (bfu*)alloc(8192ull * 1024 * 2);       // [8192][1024]
  bfu* wtfo  = (bfu*)alloc(1024ull * 4096 * 2);       // [1024][4096]
  bfu* cosb  = (bfu*)alloc(1024ull * 32 * 2);
  bfu* sinb  = (bfu*)alloc(1024ull * 32 * 2);
  bfu* inner = (bfu*)alloc(4096ull * 1024 * 2);
  bfu* qb    = (bfu*)alloc(64ull * 1024 * 64 * 2);
  bfu* kb    = (bfu*)alloc(64ull * 1024 * 64 * 2);
  bfu* vtb   = (bfu*)alloc(64ull * 1024 * 64 * 2);
  float* bqf = (float*)alloc(64ull * 1024 * 64 * 4);
  float* bkf = (float*)alloc(64ull * 1024 * 64 * 4);
  float* csum  = (float*)alloc(64ull * 8 * 64 * 4);
  float* browb = (float*)alloc(64ull * 1024 * 4);
  bfu* yb    = (bfu*)alloc(4096ull * 1024 * 2);
  bfu* ub    = (bfu*)alloc(4096ull * 8192 * 2);       // 64MB
  bfu* actb  = (bfu*)alloc(4096ull * 4096 * 2);       // 32MB (contiguous after ub)
  float* raw = (float*)ub;                            // overlay: raw proj f32 [4096][5120] = 80MB

  // weights
  wconv_t<<<dim3(32, 32), 256, 0, stream>>>(Wq,  wt5 + 0ull * 1024 * 1024, 1024, 1024);
  wconv_t<<<dim3(32, 32), 256, 0, stream>>>(Wk,  wt5 + 1ull * 1024 * 1024, 1024, 1024);
  wconv_t<<<dim3(32, 32), 256, 0, stream>>>(Wv,  wt5 + 2ull * 1024 * 1024, 1024, 1024);
  wconv_t<<<dim3(32, 32), 256, 0, stream>>>(WqB, wt5 + 3ull * 1024 * 1024, 1024, 1024);
  wconv_t<<<dim3(32, 32), 256, 0, stream>>>(WkB, wt5 + 4ull * 1024 * 1024, 1024, 1024);
  wconv_t<<<dim3(32, 32), 256, 0, stream>>>(Wo, wto, 1024, 1024);
  wconv_t<<<dim3(256, 32), 256, 0, stream>>>(Wffin, wtfi, 1024, 8192);
  wconv_t<<<dim3(32, 128), 256, 0, stream>>>(Wffout, wtfo, 4096, 1024);
  rope_tab<<<128, 256, 0, stream>>>(cosb, sinb);
  rmsnorm_k<<<4096, 256, 0, stream>>>(h, inner);

  // fused 5-way projection: [4096][1024] x [5120][1024]^T -> raw [4096][5120]
  gemm_bt<0><<<dim3(32 * 40), 256, 0, stream>>>(inner, wt5, raw, nullptr, nullptr, nullptr, nullptr,
                                                4096, 5120, 1024);

  ropenorm<true><<<16384, 256, 0, stream>>>(raw + 0,    cosb, sinb, nullptr, qb);
  ropenorm<true><<<16384, 256, 0, stream>>>(raw + 1024, cosb, sinb, nullptr, kb);
  ropenorm<false><<<16384, 256, 0, stream>>>(raw + 3072, cosb, sinb, bqf, nullptr);
  ropenorm<false><<<16384, 256, 0, stream>>>(raw + 4096, cosb, sinb, bkf, nullptr);
  vtrans<<<dim3(16, 64), 256, 0, stream>>>(raw + 2048, vtb);

  bk_chunksum<<<512, 64, 0, stream>>>(bkf, csum);
  brow_k<<<512, 64, 0, stream>>>(bqf, bkf, csum, browb);

  flash_k<<<dim3(16, 64), 256, 0, stream>>>(qb, kb, vtb, browb, l2ns, yb);

  // FFN (overwrites raw region; raw dead by now)
  gemm_bt<2><<<dim3(32 * 64), 256, 0, stream>>>(inner, wtfi, nullptr, ub, bffin, nullptr, nullptr,
                                                4096, 8192, 1024);
  silu_k<<<8192, 256, 0, stream>>>(ub, actb);
  gemm_bt<3><<<dim3(32 * 8), 256, 0, stream>>>(actb, wtfo, out, nullptr, bffout, h, lam,
                                               4096, 1024, 4096);
  // attn_out accumulate
  gemm_bt<1><<<dim3(32 * 8), 256, 0, stream>>>(yb, wto, out, nullptr, bo, nullptr, nullptr,
                                               4096, 1024, 1024);
}

// Round 2
// 477.409 us; speedup vs baseline: 1.1668x; 1.1668x over previous
//
#include <hip/hip_runtime.h>
#include <stdint.h>
#include <math.h>

typedef float f32x4 __attribute__((ext_vector_type(4)));
typedef short s16x8 __attribute__((ext_vector_type(8)));
typedef unsigned short bfu;

#define AS1q const __attribute__((address_space(1))) void*
#define AS3q __attribute__((address_space(3))) void*

static __device__ __forceinline__ float bf2f(bfu v) {
  return __uint_as_float(((unsigned int)v) << 16);
}
static __device__ __forceinline__ bfu f2bf(float f) {
  unsigned int u = __float_as_uint(f);
  return (bfu)((u + 0x7fffu + ((u >> 16) & 1u)) >> 16);
}

// ---------------- weight convert + transpose: W[K][N] f32 -> Wt[N][K] bf16 ----------------
__global__ __launch_bounds__(256) void wconv_t(const float* __restrict__ W, bfu* __restrict__ Wt,
                                               int K, int N) {
  __shared__ float t[32][33];
  int tx = threadIdx.x & 31, ty = threadIdx.x >> 5;
  int nb = blockIdx.x * 32, kb = blockIdx.y * 32;
#pragma unroll
  for (int i = 0; i < 4; i++) {
    int r = ty + i * 8;
    t[r][tx] = W[(size_t)(kb + r) * N + nb + tx];
  }
  __syncthreads();
#pragma unroll
  for (int i = 0; i < 4; i++) {
    int r = ty + i * 8;
    Wt[(size_t)(nb + r) * K + kb + tx] = f2bf(t[tx][r]);
  }
}

// batched 1024x1024 weight conversions (6 weights in one launch)
struct Ptr6 { const float* p[6]; };
__global__ __launch_bounds__(256) void wconv6(Ptr6 srcs, bfu* __restrict__ dst) {
  __shared__ float t[32][33];
  const float* W = srcs.p[blockIdx.z];
  bfu* Wt = dst + ((size_t)blockIdx.z << 20);
  int tx = threadIdx.x & 31, ty = threadIdx.x >> 5;
  int nb = blockIdx.x * 32, kb = blockIdx.y * 32;
#pragma unroll
  for (int i = 0; i < 4; i++) {
    int r = ty + i * 8;
    t[r][tx] = W[(size_t)(kb + r) * 1024 + nb + tx];
  }
  __syncthreads();
#pragma unroll
  for (int i = 0; i < 4; i++) {
    int r = ty + i * 8;
    Wt[(size_t)(nb + r) * 1024 + kb + tx] = f2bf(t[tx][r]);
  }
}

// ---------------- rope tables (bf16-rounded, matches reference) ----------------
__global__ void rope_tab(bfu* __restrict__ ct, bfu* __restrict__ st) {
  int idx = blockIdx.x * 256 + threadIdx.x;  // 1024*32
  int s = idx >> 5, i = idx & 31;
  float f = powf(1000.0f, -(float)i / 32.0f);
  float fr = (float)s * f;
  ct[idx] = f2bf(cosf(fr));
  st[idx] = f2bf(sinf(fr));
}

// ---------------- rmsnorm: h[4096][1024] f32 -> inner bf16 ----------------
__global__ __launch_bounds__(256) void rmsnorm_k(const float* __restrict__ h, bfu* __restrict__ inner) {
  int row = blockIdx.x;
  const float* hr = h + (size_t)row * 1024;
  f32x4 x = *reinterpret_cast<const f32x4*>(hr + threadIdx.x * 4);
  float ss = x[0] * x[0] + x[1] * x[1] + x[2] * x[2] + x[3] * x[3];
  for (int off = 32; off; off >>= 1) ss += __shfl_down(ss, off);
  __shared__ float wsum[4];
  int wave = threadIdx.x >> 6, lane = threadIdx.x & 63;
  if (lane == 0) wsum[wave] = ss;
  __syncthreads();
  float tot = wsum[0] + wsum[1] + wsum[2] + wsum[3];
  float r = rsqrtf(tot * (1.0f / 1024.0f) + 1.1920929e-07f);
  bfu* o = inner + (size_t)row * 1024 + threadIdx.x * 4;
  o[0] = f2bf(x[0] * r); o[1] = f2bf(x[1] * r);
  o[2] = f2bf(x[2] * r); o[3] = f2bf(x[3] * r);
}

// ---------------- GEMM: C[M][N] = A[M][K](bf16) * Bt[N][K](bf16)^T  (m97 structure) ----------------
template <int EPI>
__global__ __launch_bounds__(256) void gemm_bt(const bfu* __restrict__ A, const bfu* __restrict__ Bt,
                                               float* __restrict__ outF, bfu* __restrict__ outB,
                                               const float* __restrict__ bias,
                                               const float* __restrict__ hres,
                                               const float* __restrict__ lam,
                                               int M, int N, int K) {
  __shared__ __align__(16) char lds[32768];  // 2 bufs x (A 8KB | B 8KB)
  int nbx = N >> 7;
  int nwg = gridDim.x;
  int id = blockIdx.x;
  if ((nwg & 7) == 0) { int q = nwg >> 3; id = (id & 7) * q + (id >> 3); }  // XCD swizzle
  int bm = id / nbx, bn = id % nbx;
  int tid = threadIdx.x, wave = tid >> 6, lane = tid & 63;
  int wr = wave >> 1, wc = wave & 1;
  int g = lane >> 4, l15 = lane & 15;

  f32x4 acc[4][4];
#pragma unroll
  for (int m = 0; m < 4; m++)
#pragma unroll
    for (int n = 0; n < 4; n++) acc[m][n] = (f32x4){0.f, 0.f, 0.f, 0.f};

  auto stage = [&](int buf, int t) {
    int k0 = t << 5;
#pragma unroll
    for (int i = 0; i < 2; i++) {
      int row = (tid >> 2) + (i << 6);
      int sk = k0 + (((tid & 3) ^ (row & 3)) << 3);
      const bfu* ga = A + (size_t)(bm * 128 + row) * K + sk;
      char* la = lds + buf * 16384 + i * 4096 + wave * 1024;
      __builtin_amdgcn_global_load_lds((AS1q)ga, (AS3q)la, 16, 0, 0);
      const bfu* gb = Bt + (size_t)(bn * 128 + row) * K + sk;
      char* lb = lds + buf * 16384 + 8192 + i * 4096 + wave * 1024;
      __builtin_amdgcn_global_load_lds((AS1q)gb, (AS3q)lb, 16, 0, 0);
    }
  };

  int nt = K >> 5;
  stage(0, 0);
  __syncthreads();
  int cur = 0;
  for (int t = 0; t < nt; t++) {
    if (t + 1 < nt) stage(cur ^ 1, t + 1);
    const char* la = lds + cur * 16384;
    const char* lb = la + 8192;
    s16x8 af[4], bfr[4];
#pragma unroll
    for (int m = 0; m < 4; m++) {
      int row = wr * 64 + m * 16 + l15;
      af[m] = *reinterpret_cast<const s16x8*>(la + row * 64 + ((g ^ (row & 3)) << 4));
    }
#pragma unroll
    for (int n = 0; n < 4; n++) {
      int row = wc * 64 + n * 16 + l15;
      bfr[n] = *reinterpret_cast<const s16x8*>(lb + row * 64 + ((g ^ (row & 3)) << 4));
    }
#pragma unroll
    for (int m = 0; m < 4; m++)
#pragma unroll
      for (int n = 0; n < 4; n++)
        acc[m][n] = __builtin_amdgcn_mfma_f32_16x16x32_bf16(af[m], bfr[n], acc[m][n], 0, 0, 0);
    __syncthreads();
    cur ^= 1;
  }

  float lv = (EPI == 3) ? lam[0] : 0.0f;
#pragma unroll
  for (int m = 0; m < 4; m++) {
    int row = bm * 128 + wr * 64 + m * 16 + g * 4;
#pragma unroll
    for (int n = 0; n < 4; n++) {
      int col = bn * 128 + wc * 64 + n * 16 + l15;
#pragma unroll
      for (int r = 0; r < 4; r++) {
        float v = acc[m][n][r];
        size_t o = (size_t)(row + r) * N + col;
        if (EPI == 0) outF[o] = v;
        else if (EPI == 1) outF[o] += v + bias[col];
        else if (EPI == 2) outB[o] = f2bf(v + bias[col]);
        else outF[o] = v + bias[col] + lv * hres[o];
      }
    }
  }
}

// ---------------- l2norm + rope, all 4 projections in one launch ----------------
// raw: f32, stride 5120; which=blockIdx.y: 0->q(bf16) 1->k(bf16) 2->bq(f32) 3->bk(f32)
__global__ __launch_bounds__(256) void ropenorm4(const float* __restrict__ raw,
                                                 const bfu* __restrict__ ct, const bfu* __restrict__ st,
                                                 bfu* __restrict__ qb, bfu* __restrict__ kb,
                                                 float* __restrict__ bqf, float* __restrict__ bkf) {
  int which = blockIdx.y;
  int colofs = (which == 0) ? 0 : (which == 1) ? 1024 : (which == 2) ? 3072 : 4096;
  int wave = threadIdx.x >> 6, lane = threadIdx.x & 63;
  int idx = blockIdx.x * 4 + wave;  // (b*S+s)*16 + h, total 65536
  int h = idx & 15;
  int s = (idx >> 4) & 1023;
  int b = idx >> 14;
  size_t rowi = (size_t)(idx >> 4);
  float x = raw[rowi * 5120 + colofs + (h << 6) + lane];
  float ss = x * x;
#pragma unroll
  for (int m = 1; m < 64; m <<= 1) ss += __shfl_xor(ss, m);
  float nrm = sqrtf(ss);
  float xn = x / fmaxf(nrm, 1e-12f);
  float part = __shfl_xor(xn, 32);
  int pi = lane & 31;
  float c = bf2f(ct[(s << 5) + pi]);
  float sn = bf2f(st[(s << 5) + pi]);
  float outv = (lane < 32) ? (xn * c + part * sn) : (xn * c - part * sn);
  size_t dofs = ((size_t)((b << 4) + h) * 1024 + s) * 64 + lane;
  if (which == 0) qb[dofs] = f2bf(outv);
  else if (which == 1) kb[dofs] = f2bf(outv);
  else if (which == 2) bqf[dofs] = outv;
  else bkf[dofs] = outv;
}

// ---------------- v transpose: raw v (f32 stride 5120) -> vT bf16 [bh][d][s] ----------------
__global__ __launch_bounds__(256) void vtrans(const float* __restrict__ raw, bfu* __restrict__ vT) {
  __shared__ float t[64][65];
  int bh = blockIdx.y, stile = blockIdx.x;
  int b = bh >> 4, h = bh & 15;
  int s0 = stile << 6;
  for (int ii = threadIdx.x; ii < 4096; ii += 256) {
    int r = ii >> 6, d = ii & 63;
    t[r][d] = raw[(size_t)(b * 1024 + s0 + r) * 5120 + (h << 6) + d];
  }
  __syncthreads();
  for (int ii = threadIdx.x; ii < 4096; ii += 256) {
    int d = ii >> 6, sc = ii & 63;
    vT[((size_t)(bh * 64 + d) << 10) + s0 + sc] = f2bf(t[sc][d]);
  }
}

// ---------------- brow = scale * bq_i . prefix(bk)_i  (chunked prefix) ----------------
__global__ void bk_chunksum(const float* __restrict__ bk, float* __restrict__ csum) {
  int cid = blockIdx.x;  // bh*8 + c
  int bh = cid >> 3, c = cid & 7, lane = threadIdx.x;
  float s = 0.f;
  const float* p = bk + ((size_t)bh * 1024 + c * 128) * 64 + lane;
  for (int j = 0; j < 128; j++) s += p[(size_t)j * 64];
  csum[cid * 64 + lane] = s;
}

__global__ void brow_k(const float* __restrict__ bq, const float* __restrict__ bk,
                       const float* __restrict__ csum, float* __restrict__ brow) {
  int cid = blockIdx.x;
  int bh = cid >> 3, c = cid & 7, lane = threadIdx.x;
  float p = 0.f;
  for (int cc = 0; cc < c; cc++) p += csum[(bh * 8 + cc) * 64 + lane];
  size_t base = ((size_t)bh * 1024 + c * 128) * 64 + lane;
  for (int j = 0; j < 128; j++) {
    p += bk[base + (size_t)j * 64];
    float t = bq[base + (size_t)j * 64] * p;
#pragma unroll
    for (int m2 = 1; m2 < 64; m2 <<= 1) t += __shfl_xor(t, m2);
    if (lane == 0) brow[bh * 1024 + c * 128 + j] = 0.125f * t;
  }
}

// ---------------- flash attention: QBLK=128/block, 2 m-tiles/wave, K-prefetch pipeline ----------------
__global__ __launch_bounds__(256) void flash_k(const bfu* __restrict__ q, const bfu* __restrict__ k,
                                               const bfu* __restrict__ vT,
                                               const float* __restrict__ brow,
                                               const float* __restrict__ l2p,
                                               bfu* __restrict__ y) {
  __shared__ __align__(16) bfu P[4][2][16][72];  // 72 stride: 16B-aligned rows
  // balanced qt mapping: ids i and i+256 have qt summing to 7
  int id = blockIdx.x;  // 0..511
  int sub = id & 255;
  int qt = (id >> 8) ? 7 - (sub >> 6) : (sub >> 6);
  int bh = sub & 63;
  int wave = threadIdx.x >> 6, lane = threadIdx.x & 63;
  int g = lane >> 4, l15 = lane & 15;
  const size_t bhofs = (size_t)bh << 16;
  int rt0 = qt * 128 + wave * 32;  // m-tile m: rows rt0+m*16 .. +15

  s16x8 aq[2][2];
#pragma unroll
  for (int m = 0; m < 2; m++)
#pragma unroll
    for (int ks = 0; ks < 2; ks++)
      aq[m][ks] = *reinterpret_cast<const s16x8*>(
          q + bhofs + (size_t)(rt0 + m * 16 + l15) * 64 + ks * 32 + g * 8);

  f32x4 O[2][4];
  float mr[2][4], lr[2][4];
#pragma unroll
  for (int m = 0; m < 2; m++)
#pragma unroll
    for (int r = 0; r < 4; r++) { O[m][r] = (f32x4){0.f, 0.f, 0.f, 0.f}; mr[m][r] = -3.0e38f; lr[m][r] = 0.f; }

  s16x8 kA[4][2], kB[4][2];
  auto loadK = [&](s16x8 (&kd)[4][2], int jt) {
#pragma unroll
    for (int nt = 0; nt < 4; nt++)
#pragma unroll
      for (int ks = 0; ks < 2; ks++)
        kd[nt][ks] = *reinterpret_cast<const s16x8*>(
            k + bhofs + (size_t)(jt * 64 + nt * 16 + l15) * 64 + ks * 32 + g * 8);
  };

  int njt = 2 * qt + 2;  // always even
  loadK(kA, 0);

  auto body = [&](int jt, s16x8 (&kc)[4][2], s16x8 (&kn)[4][2], bool pf) {
    // V loads for this jt issue now, consumed after softmax
    s16x8 vv[4][2];
#pragma unroll
    for (int nt = 0; nt < 4; nt++)
#pragma unroll
      for (int ks = 0; ks < 2; ks++)
        vv[nt][ks] = *reinterpret_cast<const s16x8*>(
            vT + ((size_t)(bh * 64 + nt * 16 + l15) << 10) + jt * 64 + ks * 32 + g * 8);

    bool act[2] = { jt * 64 <= rt0 + 15, jt * 64 <= rt0 + 31 };
    f32x4 sfr[2][4];
#pragma unroll
    for (int m = 0; m < 2; m++) {
      if (!act[m]) continue;
#pragma unroll
      for (int nt = 0; nt < 4; nt++) {
        sfr[m][nt] = (f32x4){0.f, 0.f, 0.f, 0.f};
#pragma unroll
        for (int ks = 0; ks < 2; ks++)
          sfr[m][nt] = __builtin_amdgcn_mfma_f32_16x16x32_bf16(aq[m][ks], kc[nt][ks], sfr[m][nt], 0, 0, 0);
      }
    }
    // prefetch next K tile (overlaps softmax + PV)
    if (pf) loadK(kn, jt + 1);

#pragma unroll
    for (int m = 0; m < 2; m++) {
      if (!act[m]) continue;
      int rtm = rt0 + m * 16;
      if (jt * 64 + 63 > rtm) {
#pragma unroll
        for (int ntn = 0; ntn < 4; ntn++)
#pragma unroll
          for (int r = 0; r < 4; r++)
            if (jt * 64 + ntn * 16 + l15 > rtm + g * 4 + r) sfr[m][ntn][r] = -1e30f;
      }
      float alpha[4];
#pragma unroll
      for (int r = 0; r < 4; r++) {
        float v = fmaxf(fmaxf(sfr[m][0][r], sfr[m][1][r]), fmaxf(sfr[m][2][r], sfr[m][3][r]));
#pragma unroll
        for (int m2 = 1; m2 < 16; m2 <<= 1) v = fmaxf(v, __shfl_xor(v, m2));
        float mn = fmaxf(mr[m][r], v);
        alpha[r] = __expf(mr[m][r] - mn);
        mr[m][r] = mn;
      }
#pragma unroll
      for (int r = 0; r < 4; r++) {
        float rs = 0.f;
#pragma unroll
        for (int ntn = 0; ntn < 4; ntn++) {
          float e = __expf(sfr[m][ntn][r] - mr[m][r]);
          rs += e;
          P[wave][m][g * 4 + r][ntn * 16 + l15] = f2bf(e);
        }
#pragma unroll
        for (int m2 = 1; m2 < 16; m2 <<= 1) rs += __shfl_xor(rs, m2);
        lr[m][r] = lr[m][r] * alpha[r] + rs;
#pragma unroll
        for (int ntn = 0; ntn < 4; ntn++) O[m][ntn][r] *= alpha[r];
      }
    }
    asm volatile("s_waitcnt lgkmcnt(0)" ::: "memory");
    __builtin_amdgcn_sched_barrier(0);
#pragma unroll
    for (int m = 0; m < 2; m++) {
      if (!act[m]) continue;
      s16x8 pa[2];
#pragma unroll
      for (int ks = 0; ks < 2; ks++)
        pa[ks] = *reinterpret_cast<const s16x8*>(&P[wave][m][l15][ks * 32 + g * 8]);
#pragma unroll
      for (int nt = 0; nt < 4; nt++)
#pragma unroll
        for (int ks = 0; ks < 2; ks++)
          O[m][nt] = __builtin_amdgcn_mfma_f32_16x16x32_bf16(pa[ks], vv[nt][ks], O[m][nt], 0, 0, 0);
    }
  };

  for (int jt = 0; jt < njt; jt += 2) {
    body(jt, kA, kB, true);
    body(jt + 1, kB, kA, jt + 2 < njt);
  }

  float l2ns = l2p[0];
  int b = bh >> 4, h = bh & 15;
#pragma unroll
  for (int m = 0; m < 2; m++)
#pragma unroll
    for (int nt = 0; nt < 4; nt++)
#pragma unroll
      for (int r = 0; r < 4; r++) {
        int rowg = rt0 + m * 16 + g * 4 + r;
        float val = O[m][nt][r] * (l2ns / lr[m][r]) + brow[bh * 1024 + rowg];
        y[((size_t)(b * 1024 + rowg) << 10) + h * 64 + nt * 16 + l15] = f2bf(val);
      }
}

// ---------------- silu(gate)*xh ----------------
__global__ __launch_bounds__(256) void silu_k(const bfu* __restrict__ u, bfu* __restrict__ act) {
  int t = blockIdx.x * 256 + threadIdx.x;
  int row = t >> 9, cp = (t & 511) << 3;
  s16x8 xh = *reinterpret_cast<const s16x8*>(u + ((size_t)row << 13) + cp);
  s16x8 gt = *reinterpret_cast<const s16x8*>(u + ((size_t)row << 13) + 4096 + cp);
  s16x8 o;
#pragma unroll
  for (int j = 0; j < 8; j++) {
    float gv = bf2f((bfu)gt[j]);
    float xv = bf2f((bfu)xh[j]);
    float a = gv / (1.0f + __expf(-gv)) * xv;
    o[j] = (short)f2bf(a);
  }
  *reinterpret_cast<s16x8*>(act + ((size_t)row << 12) + cp) = o;
}

// ================= host =================
extern "C" void kernel_launch(void* const* d_in, const int* in_sizes, int n_in,
                              void* d_out, int out_size, void* d_ws, size_t ws_size,
                              hipStream_t stream) {
  const float* h      = (const float*)d_in[0];
  const float* Wq     = (const float*)d_in[2];
  const float* Wk     = (const float*)d_in[3];
  const float* Wv     = (const float*)d_in[4];
  const float* WqB    = (const float*)d_in[5];
  const float* WkB    = (const float*)d_in[6];
  const float* Wo     = (const float*)d_in[7];
  const float* bo     = (const float*)d_in[8];
  const float* Wffin  = (const float*)d_in[9];
  const float* bffin  = (const float*)d_in[10];
  const float* Wffout = (const float*)d_in[11];
  const float* bffout = (const float*)d_in[12];
  const float* lam    = (const float*)d_in[13];
  const float* l2ns   = (const float*)d_in[14];
  float* out = (float*)d_out;

  char* ws = (char*)d_ws;
  size_t off = 0;
  auto alloc = [&](size_t bytes) { void* p = ws + off; off += bytes; return p; };
  bfu* wt5   = (bfu*)alloc(5ull * 1024 * 1024 * 2);   // Wq..WkB transposed, contiguous [5120][1024]
  bfu* wto   = (bfu*)alloc(1ull * 1024 * 1024 * 2);   // contiguous after wt5 (wconv6 slot 5)
  bfu* wtfi  = (bfu*)alloc(8192ull * 1024 * 2);       // [8192][1024]
  bfu* wtfo  = (bfu*)alloc(1024ull * 4096 * 2);       // [1024][4096]
  bfu* cosb  = (bfu*)alloc(1024ull * 32 * 2);
  bfu* sinb  = (bfu*)alloc(1024ull * 32 * 2);
  bfu* inner = (bfu*)alloc(4096ull * 1024 * 2);
  bfu* qb    = (bfu*)alloc(64ull * 1024 * 64 * 2);
  bfu* kb    = (bfu*)alloc(64ull * 1024 * 64 * 2);
  bfu* vtb   = (bfu*)alloc(64ull * 1024 * 64 * 2);
  float* bqf = (float*)alloc(64ull * 1024 * 64 * 4);
  float* bkf = (float*)alloc(64ull * 1024 * 64 * 4);
  float* csum  = (float*)alloc(64ull * 8 * 64 * 4);
  float* browb = (float*)alloc(64ull * 1024 * 4);
  bfu* yb    = (bfu*)alloc(4096ull * 1024 * 2);
  bfu* ub    = (bfu*)alloc(4096ull * 8192 * 2);       // 64MB
  bfu* actb  = (bfu*)alloc(4096ull * 4096 * 2);       // 32MB
  float* raw = (float*)ub;                            // overlay: raw proj f32 [4096][5120] = 80MB

  // weights: 6x 1024x1024 in one launch (dst wt5||wto contiguous), 2 big ones separate
  Ptr6 p6; p6.p[0] = Wq; p6.p[1] = Wk; p6.p[2] = Wv; p6.p[3] = WqB; p6.p[4] = WkB; p6.p[5] = Wo;
  wconv6<<<dim3(32, 32, 6), 256, 0, stream>>>(p6, wt5);
  wconv_t<<<dim3(256, 32), 256, 0, stream>>>(Wffin, wtfi, 1024, 8192);
  wconv_t<<<dim3(32, 128), 256, 0, stream>>>(Wffout, wtfo, 4096, 1024);
  rope_tab<<<128, 256, 0, stream>>>(cosb, sinb);
  rmsnorm_k<<<4096, 256, 0, stream>>>(h, inner);

  // fused 5-way projection: [4096][1024] x [5120][1024]^T -> raw [4096][5120]
  gemm_bt<0><<<dim3(32 * 40), 256, 0, stream>>>(inner, wt5, raw, nullptr, nullptr, nullptr, nullptr,
                                                4096, 5120, 1024);

  ropenorm4<<<dim3(16384, 4), 256, 0, stream>>>(raw, cosb, sinb, qb, kb, bqf, bkf);
  vtrans<<<dim3(16, 64), 256, 0, stream>>>(raw + 2048, vtb);

  bk_chunksum<<<512, 64, 0, stream>>>(bkf, csum);
  brow_k<<<512, 64, 0, stream>>>(bqf, bkf, csum, browb);

  flash_k<<<dim3(512), 256, 0, stream>>>(qb, kb, vtb, browb, l2ns, yb);

  // FFN (overwrites raw region; raw dead by now)
  gemm_bt<2><<<dim3(32 * 64), 256, 0, stream>>>(inner, wtfi, nullptr, ub, bffin, nullptr, nullptr,
                                                4096, 8192, 1024);
  silu_k<<<8192, 256, 0, stream>>>(ub, actb);
  gemm_bt<3><<<dim3(32 * 8), 256, 0, stream>>>(actb, wtfo, out, nullptr, bffout, h, lam,
                                               4096, 1024, 4096);
  // attn_out accumulate
  gemm_bt<1><<<dim3(32 * 8), 256, 0, stream>>>(yb, wto, out, nullptr, bo, nullptr, nullptr,
                                               4096, 1024, 1024);
}

// Round 3
// 417.748 us; speedup vs baseline: 1.3334x; 1.1428x over previous
//
#include <hip/hip_runtime.h>
#include <stdint.h>
#include <math.h>

typedef float f32x4 __attribute__((ext_vector_type(4)));
typedef short s16x8 __attribute__((ext_vector_type(8)));
typedef unsigned short bfu;

#define AS1q const __attribute__((address_space(1))) void*
#define AS3q __attribute__((address_space(3))) void*

static __device__ __forceinline__ float bf2f(bfu v) {
  return __uint_as_float(((unsigned int)v) << 16);
}
static __device__ __forceinline__ bfu f2bf(float f) {
  unsigned int u = __float_as_uint(f);
  return (bfu)((u + 0x7fffu + ((u >> 16) & 1u)) >> 16);
}

// ---------------- weight convert + transpose ----------------
// MODE 0: Wt[n*dstride + dofs + k] = bf16(W[k][n])
// MODE 1 (ffin perm): n' = ((j>>4)<<5) | (isgate<<4) | (j&15), j=n&4095
template <int MODE>
__global__ __launch_bounds__(256) void wconv_t(const float* __restrict__ W, bfu* __restrict__ Wt,
                                               int K, int N, int dstride, int dofs) {
  __shared__ float t[32][33];
  int tx = threadIdx.x & 31, ty = threadIdx.x >> 5;
  int nb = blockIdx.x * 32, kb = blockIdx.y * 32;
#pragma unroll
  for (int i = 0; i < 4; i++) {
    int r = ty + i * 8;
    t[r][tx] = W[(size_t)(kb + r) * N + nb + tx];
  }
  __syncthreads();
#pragma unroll
  for (int i = 0; i < 4; i++) {
    int r = ty + i * 8;
    int n = nb + r;
    int nd;
    if (MODE == 1) {
      int j = n & 4095, isg = n >> 12;
      nd = ((j >> 4) << 5) | (isg << 4) | (j & 15);
    } else nd = n;
    Wt[(size_t)nd * dstride + dofs + kb + tx] = f2bf(t[tx][r]);
  }
}

// batched 1024x1024 weight conversions (5 weights in one launch)
struct Ptr5 { const float* p[5]; };
__global__ __launch_bounds__(256) void wconv5(Ptr5 srcs, bfu* __restrict__ dst) {
  __shared__ float t[32][33];
  const float* W = srcs.p[blockIdx.z];
  bfu* Wt = dst + ((size_t)blockIdx.z << 20);
  int tx = threadIdx.x & 31, ty = threadIdx.x >> 5;
  int nb = blockIdx.x * 32, kb = blockIdx.y * 32;
#pragma unroll
  for (int i = 0; i < 4; i++) {
    int r = ty + i * 8;
    t[r][tx] = W[(size_t)(kb + r) * 1024 + nb + tx];
  }
  __syncthreads();
#pragma unroll
  for (int i = 0; i < 4; i++) {
    int r = ty + i * 8;
    Wt[(size_t)(nb + r) * 1024 + kb + tx] = f2bf(t[tx][r]);
  }
}

// ---------------- rope tables ----------------
__global__ void rope_tab(bfu* __restrict__ ct, bfu* __restrict__ st) {
  int idx = blockIdx.x * 256 + threadIdx.x;  // 1024*32
  int s = idx >> 5, i = idx & 31;
  float f = powf(1000.0f, -(float)i / 32.0f);
  float fr = (float)s * f;
  ct[idx] = f2bf(cosf(fr));
  st[idx] = f2bf(sinf(fr));
}

// ---------------- rmsnorm ----------------
__global__ __launch_bounds__(256) void rmsnorm_k(const float* __restrict__ h, bfu* __restrict__ inner) {
  int row = blockIdx.x;
  const float* hr = h + (size_t)row * 1024;
  f32x4 x = *reinterpret_cast<const f32x4*>(hr + threadIdx.x * 4);
  float ss = x[0] * x[0] + x[1] * x[1] + x[2] * x[2] + x[3] * x[3];
  for (int off = 32; off; off >>= 1) ss += __shfl_down(ss, off);
  __shared__ float wsum[4];
  int wave = threadIdx.x >> 6, lane = threadIdx.x & 63;
  if (lane == 0) wsum[wave] = ss;
  __syncthreads();
  float tot = wsum[0] + wsum[1] + wsum[2] + wsum[3];
  float r = rsqrtf(tot * (1.0f / 1024.0f) + 1.1920929e-07f);
  bfu* o = inner + (size_t)row * 1024 + threadIdx.x * 4;
  o[0] = f2bf(x[0] * r); o[1] = f2bf(x[1] * r);
  o[2] = f2bf(x[2] * r); o[3] = f2bf(x[3] * r);
}

// ============ deep-pipelined 256x256 GEMM, BK=32, 3-stage LDS pipeline, 8 waves ============
// A[M][K] bf16, Bt[N][K] bf16.  EPI 0: raw f32 [M][N].  EPI 1: silu-fused -> outB bf16 stride 5120
template <int EPI>
__global__ __launch_bounds__(512, 2) void gemm256(const bfu* __restrict__ A, const bfu* __restrict__ Bt,
                                                  float* __restrict__ outF, bfu* __restrict__ outB,
                                                  const float* __restrict__ bias,
                                                  int M, int N, int K) {
  __shared__ __align__(16) char lds[98304];  // 3 x (A 16KB | B 16KB)
  int nbx = N >> 8;
  int nwg = gridDim.x;
  int id = blockIdx.x;
  { int q = nwg >> 3; id = (id & 7) * q + (id >> 3); }  // XCD swizzle (nwg%8==0)
  int bm = id / nbx, bn = id % nbx;
  int tid = threadIdx.x, w = tid >> 6, lane = tid & 63;
  int wm = w >> 2, wn = w & 3;
  int g = lane >> 4, l15 = lane & 15;
  int NT = K >> 5;

  f32x4 acc[8][4];
#pragma unroll
  for (int m = 0; m < 8; m++)
#pragma unroll
    for (int n = 0; n < 4; n++) acc[m][n] = (f32x4){0.f, 0.f, 0.f, 0.f};

  auto stageA = [&](int buf, int t) {
    int k0 = t << 5;
#pragma unroll
    for (int r = 0; r < 2; r++) {
      int L = r * 512 + tid;
      int row = L >> 2, c = L & 3;
      int kc = c ^ (row & 3);
      const bfu* src = A + (size_t)(bm * 256 + row) * K + k0 + kc * 8;
      char* dst = lds + buf * 32768 + r * 8192 + w * 1024;  // wave-uniform base
      __builtin_amdgcn_global_load_lds((AS1q)src, (AS3q)dst, 16, 0, 0);
    }
  };
  auto stageB = [&](int buf, int t) {
    int k0 = t << 5;
#pragma unroll
    for (int r = 0; r < 2; r++) {
      int L = r * 512 + tid;
      int row = L >> 2, c = L & 3;
      int kc = c ^ (row & 3);
      const bfu* src = Bt + (size_t)(bn * 256 + row) * K + k0 + kc * 8;
      char* dst = lds + buf * 32768 + 16384 + r * 8192 + w * 1024;
      __builtin_amdgcn_global_load_lds((AS1q)src, (AS3q)dst, 16, 0, 0);
    }
  };

  // prologue: tiles 0,1
  stageA(0, 0); stageB(0, 0);
  stageA(1, 1); stageB(1, 1);
  asm volatile("s_waitcnt vmcnt(4)" ::: "memory");
  __builtin_amdgcn_s_barrier();
  __builtin_amdgcn_sched_barrier(0);

  int bc = 0;
  for (int t = 0; t < NT; t++) {
    int bs = bc + 2; if (bs >= 3) bs -= 3;
    bool pf = (t + 2) < NT;
    const char* la = lds + bc * 32768;
    const char* lb = la + 16384;
    // ---- phase A: stage A(t+2); compute m0-3 x n0-3 ----
    if (pf) stageA(bs, t + 2);
    s16x8 af[4], bfr[4];
#pragma unroll
    for (int m = 0; m < 4; m++) {
      int row = wm * 128 + m * 16 + l15;
      af[m] = *reinterpret_cast<const s16x8*>(la + row * 64 + ((g ^ (row & 3)) << 4));
    }
#pragma unroll
    for (int n = 0; n < 4; n++) {
      int row = wn * 64 + n * 16 + l15;
      bfr[n] = *reinterpret_cast<const s16x8*>(lb + row * 64 + ((g ^ (row & 3)) << 4));
    }
    asm volatile("s_waitcnt lgkmcnt(0)" ::: "memory");
    __builtin_amdgcn_sched_barrier(0);
    __builtin_amdgcn_s_setprio(1);
#pragma unroll
    for (int m = 0; m < 4; m++)
#pragma unroll
      for (int n = 0; n < 4; n++)
        acc[m][n] = __builtin_amdgcn_mfma_f32_16x16x32_bf16(af[m], bfr[n], acc[m][n], 0, 0, 0);
    __builtin_amdgcn_s_setprio(0);
    __builtin_amdgcn_sched_barrier(0);
    __builtin_amdgcn_s_barrier();
    // ---- phase B: stage B(t+2); compute m4-7 x n0-3 ----
    if (pf) stageB(bs, t + 2);
#pragma unroll
    for (int m = 0; m < 4; m++) {
      int row = wm * 128 + 64 + m * 16 + l15;
      af[m] = *reinterpret_cast<const s16x8*>(la + row * 64 + ((g ^ (row & 3)) << 4));
    }
    asm volatile("s_waitcnt lgkmcnt(0)" ::: "memory");
    __builtin_amdgcn_sched_barrier(0);
    __builtin_amdgcn_s_setprio(1);
#pragma unroll
    for (int m = 0; m < 4; m++)
#pragma unroll
      for (int n = 0; n < 4; n++)
        acc[m + 4][n] = __builtin_amdgcn_mfma_f32_16x16x32_bf16(af[m], bfr[n], acc[m + 4][n], 0, 0, 0);
    __builtin_amdgcn_s_setprio(0);
    __builtin_amdgcn_sched_barrier(0);
    if (t < NT - 2) { asm volatile("s_waitcnt vmcnt(4)" ::: "memory"); }
    else            { asm volatile("s_waitcnt vmcnt(0)" ::: "memory"); }
    __builtin_amdgcn_s_barrier();
    __builtin_amdgcn_sched_barrier(0);
    bc++; if (bc == 3) bc = 0;
  }

  // epilogue
#pragma unroll
  for (int m = 0; m < 8; m++) {
    int row = bm * 256 + wm * 128 + m * 16 + g * 4;
    if (EPI == 0) {
#pragma unroll
      for (int n = 0; n < 4; n++) {
        int col = bn * 256 + wn * 64 + n * 16 + l15;
#pragma unroll
        for (int r = 0; r < 4; r++) outF[(size_t)(row + r) * N + col] = acc[m][n][r];
      }
    } else {
#pragma unroll
      for (int n = 0; n < 4; n += 2) {
        int np = bn * 256 + wn * 64 + n * 16 + l15;
        int j = ((np >> 5) << 4) | (np & 15);
        float bx = bias[j], bg = bias[j + 4096];
#pragma unroll
        for (int r = 0; r < 4; r++) {
          float xh = acc[m][n][r] + bx;
          float gt = acc[m][n + 1][r] + bg;
          float v = gt / (1.0f + __expf(-gt)) * xh;
          outB[(size_t)(row + r) * 5120 + j] = f2bf(v);
        }
      }
    }
  }
}

// ============ deep-pipelined 128x128 GEMM, BK=32, 3-stage pipeline, 4 waves ============
// final: out = A(AB,stride=K=5120) x Btc^T + bffout + bo + lam*h
__global__ __launch_bounds__(256, 3) void gemm128f(const bfu* __restrict__ A, const bfu* __restrict__ Bt,
                                                   float* __restrict__ out,
                                                   const float* __restrict__ b1,
                                                   const float* __restrict__ b2,
                                                   const float* __restrict__ lam,
                                                   const float* __restrict__ h,
                                                   int M, int N, int K) {
  __shared__ __align__(16) char lds[49152];  // 3 x (A 8KB | B 8KB)
  int nbx = N >> 7;
  int nwg = gridDim.x;
  int id = blockIdx.x;
  { int q = nwg >> 3; id = (id & 7) * q + (id >> 3); }
  int bm = id / nbx, bn = id % nbx;
  int tid = threadIdx.x, w = tid >> 6, lane = tid & 63;
  int wm = w >> 1, wn = w & 1;
  int g = lane >> 4, l15 = lane & 15;
  int NT = K >> 5;

  f32x4 acc[4][4];
#pragma unroll
  for (int m = 0; m < 4; m++)
#pragma unroll
    for (int n = 0; n < 4; n++) acc[m][n] = (f32x4){0.f, 0.f, 0.f, 0.f};

  auto stage = [&](int buf, int t) {
    int k0 = t << 5;
#pragma unroll
    for (int r = 0; r < 2; r++) {
      int L = r * 256 + tid;
      int row = L >> 2, c = L & 3;
      int kc = c ^ (row & 3);
      const bfu* srcA = A + (size_t)(bm * 128 + row) * K + k0 + kc * 8;
      char* dstA = lds + buf * 16384 + r * 4096 + w * 1024;
      __builtin_amdgcn_global_load_lds((AS1q)srcA, (AS3q)dstA, 16, 0, 0);
      const bfu* srcB = Bt + (size_t)(bn * 128 + row) * K + k0 + kc * 8;
      char* dstB = lds + buf * 16384 + 8192 + r * 4096 + w * 1024;
      __builtin_amdgcn_global_load_lds((AS1q)srcB, (AS3q)dstB, 16, 0, 0);
    }
  };

  stage(0, 0); stage(1, 1);
  asm volatile("s_waitcnt vmcnt(4)" ::: "memory");
  __builtin_amdgcn_s_barrier();
  __builtin_amdgcn_sched_barrier(0);

  int bc = 0;
  for (int t = 0; t < NT; t++) {
    int bs = bc + 2; if (bs >= 3) bs -= 3;
    if (t + 2 < NT) stage(bs, t + 2);
    const char* la = lds + bc * 16384;
    const char* lb = la + 8192;
    s16x8 af[4], bfr[4];
#pragma unroll
    for (int m = 0; m < 4; m++) {
      int row = wm * 64 + m * 16 + l15;
      af[m] = *reinterpret_cast<const s16x8*>(la + row * 64 + ((g ^ (row & 3)) << 4));
    }
#pragma unroll
    for (int n = 0; n < 4; n++) {
      int row = wn * 64 + n * 16 + l15;
      bfr[n] = *reinterpret_cast<const s16x8*>(lb + row * 64 + ((g ^ (row & 3)) << 4));
    }
    asm volatile("s_waitcnt lgkmcnt(0)" ::: "memory");
    __builtin_amdgcn_sched_barrier(0);
    __builtin_amdgcn_s_setprio(1);
#pragma unroll
    for (int m = 0; m < 4; m++)
#pragma unroll
      for (int n = 0; n < 4; n++)
        acc[m][n] = __builtin_amdgcn_mfma_f32_16x16x32_bf16(af[m], bfr[n], acc[m][n], 0, 0, 0);
    __builtin_amdgcn_s_setprio(0);
    __builtin_amdgcn_sched_barrier(0);
    if (t < NT - 2) { asm volatile("s_waitcnt vmcnt(4)" ::: "memory"); }
    else            { asm volatile("s_waitcnt vmcnt(0)" ::: "memory"); }
    __builtin_amdgcn_s_barrier();
    __builtin_amdgcn_sched_barrier(0);
    bc++; if (bc == 3) bc = 0;
  }

  float lv = lam[0];
#pragma unroll
  for (int m = 0; m < 4; m++) {
    int row = bm * 128 + wm * 64 + m * 16 + g * 4;
#pragma unroll
    for (int n = 0; n < 4; n++) {
      int col = bn * 128 + wn * 64 + n * 16 + l15;
      float bb = b1[col] + b2[col];
#pragma unroll
      for (int r = 0; r < 4; r++) {
        size_t o = (size_t)(row + r) * 1024 + col;
        out[o] = acc[m][n][r] + bb + lv * h[o];
      }
    }
  }
}

// ---------------- l2norm + rope, all 4 projections ----------------
__global__ __launch_bounds__(256) void ropenorm4(const float* __restrict__ raw,
                                                 const bfu* __restrict__ ct, const bfu* __restrict__ st,
                                                 bfu* __restrict__ qb, bfu* __restrict__ kb,
                                                 float* __restrict__ bqf, float* __restrict__ bkf) {
  int which = blockIdx.y;
  int colofs = (which == 0) ? 0 : (which == 1) ? 1024 : (which == 2) ? 3072 : 4096;
  int wave = threadIdx.x >> 6, lane = threadIdx.x & 63;
  int idx = blockIdx.x * 4 + wave;
  int h = idx & 15;
  int s = (idx >> 4) & 1023;
  int b = idx >> 14;
  size_t rowi = (size_t)(idx >> 4);
  float x = raw[rowi * 5120 + colofs + (h << 6) + lane];
  float ss = x * x;
#pragma unroll
  for (int m = 1; m < 64; m <<= 1) ss += __shfl_xor(ss, m);
  float nrm = sqrtf(ss);
  float xn = x / fmaxf(nrm, 1e-12f);
  float part = __shfl_xor(xn, 32);
  int pi = lane & 31;
  float c = bf2f(ct[(s << 5) + pi]);
  float sn = bf2f(st[(s << 5) + pi]);
  float outv = (lane < 32) ? (xn * c + part * sn) : (xn * c - part * sn);
  size_t dofs = ((size_t)((b << 4) + h) * 1024 + s) * 64 + lane;
  if (which == 0) qb[dofs] = f2bf(outv);
  else if (which == 1) kb[dofs] = f2bf(outv);
  else if (which == 2) bqf[dofs] = outv;
  else bkf[dofs] = outv;
}

// ---------------- v transpose ----------------
__global__ __launch_bounds__(256) void vtrans(const float* __restrict__ raw, bfu* __restrict__ vT) {
  __shared__ float t[64][65];
  int bh = blockIdx.y, stile = blockIdx.x;
  int b = bh >> 4, h = bh & 15;
  int s0 = stile << 6;
  for (int ii = threadIdx.x; ii < 4096; ii += 256) {
    int r = ii >> 6, d = ii & 63;
    t[r][d] = raw[(size_t)(b * 1024 + s0 + r) * 5120 + (h << 6) + d];
  }
  __syncthreads();
  for (int ii = threadIdx.x; ii < 4096; ii += 256) {
    int d = ii >> 6, sc = ii & 63;
    vT[((size_t)(bh * 64 + d) << 10) + s0 + sc] = f2bf(t[sc][d]);
  }
}

// ---------------- brow ----------------
__global__ void bk_chunksum(const float* __restrict__ bk, float* __restrict__ csum) {
  int cid = blockIdx.x;
  int bh = cid >> 3, c = cid & 7, lane = threadIdx.x;
  float s = 0.f;
  const float* p = bk + ((size_t)bh * 1024 + c * 128) * 64 + lane;
  for (int j = 0; j < 128; j++) s += p[(size_t)j * 64];
  csum[cid * 64 + lane] = s;
}

__global__ void brow_k(const float* __restrict__ bq, const float* __restrict__ bk,
                       const float* __restrict__ csum, float* __restrict__ brow) {
  int cid = blockIdx.x;
  int bh = cid >> 3, c = cid & 7, lane = threadIdx.x;
  float p = 0.f;
  for (int cc = 0; cc < c; cc++) p += csum[(bh * 8 + cc) * 64 + lane];
  size_t base = ((size_t)bh * 1024 + c * 128) * 64 + lane;
  for (int j = 0; j < 128; j++) {
    p += bk[base + (size_t)j * 64];
    float t = bq[base + (size_t)j * 64] * p;
#pragma unroll
    for (int m2 = 1; m2 < 64; m2 <<= 1) t += __shfl_xor(t, m2);
    if (lane == 0) brow[bh * 1024 + c * 128 + j] = 0.125f * t;
  }
}

// ---------------- flash attention (writes y into AB cols 4096.. stride 5120) ----------------
__global__ __launch_bounds__(256) void flash_k(const bfu* __restrict__ q, const bfu* __restrict__ k,
                                               const bfu* __restrict__ vT,
                                               const float* __restrict__ brow,
                                               const float* __restrict__ l2p,
                                               bfu* __restrict__ y) {
  __shared__ __align__(16) bfu P[4][2][16][72];
  int id = blockIdx.x;  // 0..511
  int sub = id & 255;
  int qt = (id >> 8) ? 7 - (sub >> 6) : (sub >> 6);
  int bh = sub & 63;
  int wave = threadIdx.x >> 6, lane = threadIdx.x & 63;
  int g = lane >> 4, l15 = lane & 15;
  const size_t bhofs = (size_t)bh << 16;
  int rt0 = qt * 128 + wave * 32;

  s16x8 aq[2][2];
#pragma unroll
  for (int m = 0; m < 2; m++)
#pragma unroll
    for (int ks = 0; ks < 2; ks++)
      aq[m][ks] = *reinterpret_cast<const s16x8*>(
          q + bhofs + (size_t)(rt0 + m * 16 + l15) * 64 + ks * 32 + g * 8);

  f32x4 O[2][4];
  float mr[2][4], lr[2][4];
#pragma unroll
  for (int m = 0; m < 2; m++)
#pragma unroll
    for (int r = 0; r < 4; r++) { O[m][r] = (f32x4){0.f, 0.f, 0.f, 0.f}; mr[m][r] = -3.0e38f; lr[m][r] = 0.f; }

  s16x8 kA[4][2], kB[4][2];
  auto loadK = [&](s16x8 (&kd)[4][2], int jt) {
#pragma unroll
    for (int nt = 0; nt < 4; nt++)
#pragma unroll
      for (int ks = 0; ks < 2; ks++)
        kd[nt][ks] = *reinterpret_cast<const s16x8*>(
            k + bhofs + (size_t)(jt * 64 + nt * 16 + l15) * 64 + ks * 32 + g * 8);
  };

  int njt = 2 * qt + 2;
  loadK(kA, 0);

  auto body = [&](int jt, s16x8 (&kc)[4][2], s16x8 (&kn)[4][2], bool pf) {
    s16x8 vv[4][2];
#pragma unroll
    for (int nt = 0; nt < 4; nt++)
#pragma unroll
      for (int ks = 0; ks < 2; ks++)
        vv[nt][ks] = *reinterpret_cast<const s16x8*>(
            vT + ((size_t)(bh * 64 + nt * 16 + l15) << 10) + jt * 64 + ks * 32 + g * 8);

    bool act[2] = { jt * 64 <= rt0 + 15, jt * 64 <= rt0 + 31 };
    f32x4 sfr[2][4];
#pragma unroll
    for (int m = 0; m < 2; m++) {
      if (!act[m]) continue;
#pragma unroll
      for (int nt = 0; nt < 4; nt++) {
        sfr[m][nt] = (f32x4){0.f, 0.f, 0.f, 0.f};
#pragma unroll
        for (int ks = 0; ks < 2; ks++)
          sfr[m][nt] = __builtin_amdgcn_mfma_f32_16x16x32_bf16(aq[m][ks], kc[nt][ks], sfr[m][nt], 0, 0, 0);
      }
    }
    if (pf) loadK(kn, jt + 1);

#pragma unroll
    for (int m = 0; m < 2; m++) {
      if (!act[m]) continue;
      int rtm = rt0 + m * 16;
      if (jt * 64 + 63 > rtm) {
#pragma unroll
        for (int ntn = 0; ntn < 4; ntn++)
#pragma unroll
          for (int r = 0; r < 4; r++)
            if (jt * 64 + ntn * 16 + l15 > rtm + g * 4 + r) sfr[m][ntn][r] = -1e30f;
      }
      float alpha[4];
#pragma unroll
      for (int r = 0; r < 4; r++) {
        float v = fmaxf(fmaxf(sfr[m][0][r], sfr[m][1][r]), fmaxf(sfr[m][2][r], sfr[m][3][r]));
#pragma unroll
        for (int m2 = 1; m2 < 16; m2 <<= 1) v = fmaxf(v, __shfl_xor(v, m2));
        float mn = fmaxf(mr[m][r], v);
        alpha[r] = __expf(mr[m][r] - mn);
        mr[m][r] = mn;
      }
#pragma unroll
      for (int r = 0; r < 4; r++) {
        float rs = 0.f;
#pragma unroll
        for (int ntn = 0; ntn < 4; ntn++) {
          float e = __expf(sfr[m][ntn][r] - mr[m][r]);
          rs += e;
          P[wave][m][g * 4 + r][ntn * 16 + l15] = f2bf(e);
        }
#pragma unroll
        for (int m2 = 1; m2 < 16; m2 <<= 1) rs += __shfl_xor(rs, m2);
        lr[m][r] = lr[m][r] * alpha[r] + rs;
#pragma unroll
        for (int ntn = 0; ntn < 4; ntn++) O[m][ntn][r] *= alpha[r];
      }
    }
    asm volatile("s_waitcnt lgkmcnt(0)" ::: "memory");
    __builtin_amdgcn_sched_barrier(0);
#pragma unroll
    for (int m = 0; m < 2; m++) {
      if (!act[m]) continue;
      s16x8 pa[2];
#pragma unroll
      for (int ks = 0; ks < 2; ks++)
        pa[ks] = *reinterpret_cast<const s16x8*>(&P[wave][m][l15][ks * 32 + g * 8]);
#pragma unroll
      for (int nt = 0; nt < 4; nt++)
#pragma unroll
        for (int ks = 0; ks < 2; ks++)
          O[m][nt] = __builtin_amdgcn_mfma_f32_16x16x32_bf16(pa[ks], vv[nt][ks], O[m][nt], 0, 0, 0);
    }
  };

  for (int jt = 0; jt < njt; jt += 2) {
    body(jt, kA, kB, true);
    body(jt + 1, kB, kA, jt + 2 < njt);
  }

  float l2ns = l2p[0];
  int b = bh >> 4, h = bh & 15;
#pragma unroll
  for (int m = 0; m < 2; m++)
#pragma unroll
    for (int nt = 0; nt < 4; nt++)
#pragma unroll
      for (int r = 0; r < 4; r++) {
        int rowg = rt0 + m * 16 + g * 4 + r;
        float val = O[m][nt][r] * (l2ns / lr[m][r]) + brow[bh * 1024 + rowg];
        y[(size_t)(b * 1024 + rowg) * 5120 + 4096 + h * 64 + nt * 16 + l15] = f2bf(val);
      }
}

// ================= host =================
extern "C" void kernel_launch(void* const* d_in, const int* in_sizes, int n_in,
                              void* d_out, int out_size, void* d_ws, size_t ws_size,
                              hipStream_t stream) {
  const float* h      = (const float*)d_in[0];
  const float* Wq     = (const float*)d_in[2];
  const float* Wk     = (const float*)d_in[3];
  const float* Wv     = (const float*)d_in[4];
  const float* WqB    = (const float*)d_in[5];
  const float* WkB    = (const float*)d_in[6];
  const float* Wo     = (const float*)d_in[7];
  const float* bo     = (const float*)d_in[8];
  const float* Wffin  = (const float*)d_in[9];
  const float* bffin  = (const float*)d_in[10];
  const float* Wffout = (const float*)d_in[11];
  const float* bffout = (const float*)d_in[12];
  const float* lam    = (const float*)d_in[13];
  const float* l2ns   = (const float*)d_in[14];
  float* out = (float*)d_out;

  char* ws = (char*)d_ws;
  size_t off = 0;
  auto alloc = [&](size_t bytes) { void* p = ws + off; off += bytes; return p; };
  bfu* wt5   = (bfu*)alloc(5ull * 1024 * 1024 * 2);   // [5120][1024]
  bfu* wtfi  = (bfu*)alloc(8192ull * 1024 * 2);       // [8192][1024] (perm rows)
  bfu* wtfoc = (bfu*)alloc(1024ull * 5120 * 2);       // [1024][5120] = Wffout_t | Wo_t
  bfu* cosb  = (bfu*)alloc(1024ull * 32 * 2);
  bfu* sinb  = (bfu*)alloc(1024ull * 32 * 2);
  bfu* inner = (bfu*)alloc(4096ull * 1024 * 2);
  bfu* qb    = (bfu*)alloc(64ull * 1024 * 64 * 2);
  bfu* kb    = (bfu*)alloc(64ull * 1024 * 64 * 2);
  bfu* vtb   = (bfu*)alloc(64ull * 1024 * 64 * 2);
  float* bqf = (float*)alloc(64ull * 1024 * 64 * 4);
  float* bkf = (float*)alloc(64ull * 1024 * 64 * 4);
  float* csum  = (float*)alloc(64ull * 8 * 64 * 4);
  float* browb = (float*)alloc(64ull * 1024 * 4);
  float* raw = (float*)alloc(4096ull * 5120 * 4);     // 80MB; AB overlays it
  bfu* AB    = (bfu*)raw;                             // [4096][5120] bf16: act | y

  // weights
  Ptr5 p5; p5.p[0] = Wq; p5.p[1] = Wk; p5.p[2] = Wv; p5.p[3] = WqB; p5.p[4] = WkB;
  wconv5<<<dim3(32, 32, 5), 256, 0, stream>>>(p5, wt5);
  wconv_t<1><<<dim3(256, 32), 256, 0, stream>>>(Wffin, wtfi, 1024, 8192, 1024, 0);
  wconv_t<0><<<dim3(32, 128), 256, 0, stream>>>(Wffout, wtfoc, 4096, 1024, 5120, 0);
  wconv_t<0><<<dim3(32, 32), 256, 0, stream>>>(Wo, wtfoc, 1024, 1024, 5120, 4096);
  rope_tab<<<128, 256, 0, stream>>>(cosb, sinb);
  rmsnorm_k<<<4096, 256, 0, stream>>>(h, inner);

  // fused 5-way projection -> raw [4096][5120] f32
  gemm256<0><<<dim3(16 * 20), 512, 0, stream>>>(inner, wt5, raw, nullptr, nullptr, 4096, 5120, 1024);

  ropenorm4<<<dim3(16384, 4), 256, 0, stream>>>(raw, cosb, sinb, qb, kb, bqf, bkf);
  vtrans<<<dim3(16, 64), 256, 0, stream>>>(raw + 2048, vtb);

  bk_chunksum<<<512, 64, 0, stream>>>(bkf, csum);
  brow_k<<<512, 64, 0, stream>>>(bqf, bkf, csum, browb);

  // flash writes y into AB cols 4096.. (raw is dead after ropenorm4+vtrans)
  flash_k<<<dim3(512), 256, 0, stream>>>(qb, kb, vtb, browb, l2ns, AB);

  // FF-in + silu fused -> AB cols 0..4095
  gemm256<1><<<dim3(16 * 32), 512, 0, stream>>>(inner, wtfi, nullptr, AB, bffin, 4096, 8192, 1024);

  // final merged: out = AB @ [Wffout|Wo]^T + bffout + bo + lam*h
  gemm128f<<<dim3(32 * 8), 256, 0, stream>>>(AB, wtfoc, out, bffout, bo, lam, h, 4096, 1024, 5120);
}

// Round 4
// 405.454 us; speedup vs baseline: 1.3739x; 1.0303x over previous
//
#include <hip/hip_runtime.h>
#include <stdint.h>
#include <math.h>

typedef float f32x4 __attribute__((ext_vector_type(4)));
typedef short s16x8 __attribute__((ext_vector_type(8)));
typedef unsigned short bfu;

#define AS1q const __attribute__((address_space(1))) void*
#define AS3q __attribute__((address_space(3))) void*

static __device__ __forceinline__ float bf2f(bfu v) {
  return __uint_as_float(((unsigned int)v) << 16);
}
static __device__ __forceinline__ bfu f2bf(float f) {
  unsigned int u = __float_as_uint(f);
  return (bfu)((u + 0x7fffu + ((u >> 16) & 1u)) >> 16);
}

// ---------------- weight convert + transpose ----------------
// MODE 0: Wt[n*dstride + dofs + k] = bf16(W[k][n])
// MODE 1 (ffin perm): n' = ((j>>4)<<5) | (isgate<<4) | (j&15), j=n&4095
template <int MODE>
__global__ __launch_bounds__(256) void wconv_t(const float* __restrict__ W, bfu* __restrict__ Wt,
                                               int K, int N, int dstride, int dofs) {
  __shared__ float t[32][33];
  int tx = threadIdx.x & 31, ty = threadIdx.x >> 5;
  int nb = blockIdx.x * 32, kb = blockIdx.y * 32;
#pragma unroll
  for (int i = 0; i < 4; i++) {
    int r = ty + i * 8;
    t[r][tx] = W[(size_t)(kb + r) * N + nb + tx];
  }
  __syncthreads();
#pragma unroll
  for (int i = 0; i < 4; i++) {
    int r = ty + i * 8;
    int n = nb + r;
    int nd;
    if (MODE == 1) {
      int j = n & 4095, isg = n >> 12;
      nd = ((j >> 4) << 5) | (isg << 4) | (j & 15);
    } else nd = n;
    Wt[(size_t)nd * dstride + dofs + kb + tx] = f2bf(t[tx][r]);
  }
}

// batched 1024x1024 weight conversions (5 weights in one launch)
struct Ptr5 { const float* p[5]; };
__global__ __launch_bounds__(256) void wconv5(Ptr5 srcs, bfu* __restrict__ dst) {
  __shared__ float t[32][33];
  const float* W = srcs.p[blockIdx.z];
  bfu* Wt = dst + ((size_t)blockIdx.z << 20);
  int tx = threadIdx.x & 31, ty = threadIdx.x >> 5;
  int nb = blockIdx.x * 32, kb = blockIdx.y * 32;
#pragma unroll
  for (int i = 0; i < 4; i++) {
    int r = ty + i * 8;
    t[r][tx] = W[(size_t)(kb + r) * 1024 + nb + tx];
  }
  __syncthreads();
#pragma unroll
  for (int i = 0; i < 4; i++) {
    int r = ty + i * 8;
    Wt[(size_t)(nb + r) * 1024 + kb + tx] = f2bf(t[tx][r]);
  }
}

// ---------------- rope tables ----------------
__global__ void rope_tab(bfu* __restrict__ ct, bfu* __restrict__ st) {
  int idx = blockIdx.x * 256 + threadIdx.x;  // 1024*32
  int s = idx >> 5, i = idx & 31;
  float f = powf(1000.0f, -(float)i / 32.0f);
  float fr = (float)s * f;
  ct[idx] = f2bf(cosf(fr));
  st[idx] = f2bf(sinf(fr));
}

// ---------------- rmsnorm ----------------
__global__ __launch_bounds__(256) void rmsnorm_k(const float* __restrict__ h, bfu* __restrict__ inner) {
  int row = blockIdx.x;
  const float* hr = h + (size_t)row * 1024;
  f32x4 x = *reinterpret_cast<const f32x4*>(hr + threadIdx.x * 4);
  float ss = x[0] * x[0] + x[1] * x[1] + x[2] * x[2] + x[3] * x[3];
  for (int off = 32; off; off >>= 1) ss += __shfl_down(ss, off);
  __shared__ float wsum[4];
  int wave = threadIdx.x >> 6, lane = threadIdx.x & 63;
  if (lane == 0) wsum[wave] = ss;
  __syncthreads();
  float tot = wsum[0] + wsum[1] + wsum[2] + wsum[3];
  float r = rsqrtf(tot * (1.0f / 1024.0f) + 1.1920929e-07f);
  bfu* o = inner + (size_t)row * 1024 + threadIdx.x * 4;
  o[0] = f2bf(x[0] * r); o[1] = f2bf(x[1] * r);
  o[2] = f2bf(x[2] * r); o[3] = f2bf(x[3] * r);
}

// ============ 8-phase 256x256 GEMM, BK=64, 2-dbuf LDS, counted vmcnt (m201-style) ============
// A[M][K] bf16, Bt[N][K] bf16.  EPI 0: raw f32 [M][N].  EPI 1: silu-fused -> outB bf16 stride 5120
// LDS: [dbuf=kt&1][mat A/B][half 128 rows][128B rows, chunk^=(row&7) swizzle] = 128KB
template <int EPI>
__global__ __launch_bounds__(512, 2) void gemm256p(const bfu* __restrict__ A, const bfu* __restrict__ Bt,
                                                   float* __restrict__ outF, bfu* __restrict__ outB,
                                                   const float* __restrict__ bias,
                                                   int M, int N, int K) {
  __shared__ __align__(16) char lds[131072];
  int nbx = N >> 8;
  int nwg = gridDim.x;
  int id = blockIdx.x;
  { int q = nwg >> 3; id = (id & 7) * q + (id >> 3); }  // XCD swizzle (nwg%8==0)
  int bm = id / nbx, bn = id % nbx;
  int tid = threadIdx.x, w = tid >> 6, lane = tid & 63;
  int wm = w >> 2, wn = w & 3;
  int g = lane >> 4, l15 = lane & 15;
  int NT = K >> 6;   // BK=64 tiles (must be even)
  int NI = NT >> 1;

  f32x4 acc[8][4];
#pragma unroll
  for (int m = 0; m < 8; m++)
#pragma unroll
    for (int n = 0; n < 4; n++) acc[m][n] = (f32x4){0.f, 0.f, 0.f, 0.f};

  s16x8 af[4][2];   // current quadrant A frags (4 m x 2 ks)
  s16x8 bfr[4][2];  // all 4 n-frags of wave's 64-col strip

  // stage one half-tile (2 global_load_lds / thread). mat 0=A 1=B.
  auto stage = [&](int mat, int kt, int hf) {
    if (kt >= NT) return;
    int d = kt & 1;
    const bfu* s0 = (mat == 0) ? A : Bt;
    int rowbase = ((mat == 0) ? bm : bn) * 256 + hf * 128;
    int k0 = kt << 6;
    char* base = lds + d * 65536 + mat * 32768 + hf * 16384;
#pragma unroll
    for (int r = 0; r < 2; r++) {
      int L = r * 512 + tid;
      int row = L >> 3, c = L & 7;
      int kc = c ^ (row & 7);
      const bfu* src = s0 + (size_t)(rowbase + row) * K + k0 + kc * 8;
      char* dst = base + r * 8192 + w * 1024;
      __builtin_amdgcn_global_load_lds((AS1q)src, (AS3q)dst, 16, 0, 0);
    }
  };

  auto ldA = [&](int d, int mh) {
    const char* base = lds + d * 65536 + wm * 16384;
#pragma unroll
    for (int mm = 0; mm < 4; mm++) {
      int row = mh * 64 + mm * 16 + l15;
#pragma unroll
      for (int ks = 0; ks < 2; ks++)
        af[mm][ks] = *reinterpret_cast<const s16x8*>(
            base + row * 128 + (((ks * 4 + g) ^ (row & 7)) << 4));
    }
  };
  auto ldB2 = [&](int d, int nh) {
    const char* base = lds + d * 65536 + 32768 + (wn >> 1) * 16384;
#pragma unroll
    for (int nn = 0; nn < 2; nn++) {
      int row = (wn & 1) * 64 + (nh * 2 + nn) * 16 + l15;
#pragma unroll
      for (int ks = 0; ks < 2; ks++)
        bfr[nh * 2 + nn][ks] = *reinterpret_cast<const s16x8*>(
            base + row * 128 + (((ks * 4 + g) ^ (row & 7)) << 4));
    }
  };
  auto mfma_q = [&](int mh, int nh) {
    asm volatile("s_waitcnt lgkmcnt(0)" ::: "memory");
    __builtin_amdgcn_sched_barrier(0);
    __builtin_amdgcn_s_barrier();
    __builtin_amdgcn_s_setprio(1);
#pragma unroll
    for (int mm = 0; mm < 4; mm++)
#pragma unroll
      for (int nn = 0; nn < 2; nn++) {
        int n = nh * 2 + nn, m = mh * 4 + mm;
#pragma unroll
        for (int ks = 0; ks < 2; ks++)
          acc[m][n] = __builtin_amdgcn_mfma_f32_16x16x32_bf16(af[mm][ks], bfr[n][ks], acc[m][n], 0, 0, 0);
      }
    __builtin_amdgcn_s_setprio(0);
    __builtin_amdgcn_sched_barrier(0);
  };

  // prologue: tile 0 (all 4 halves) + B(1) both halves; leave B(1) in flight
  stage(1, 0, 0); stage(0, 0, 0); stage(0, 0, 1); stage(1, 0, 1);
  stage(1, 1, 0); stage(1, 1, 1);
  asm volatile("s_waitcnt vmcnt(4)" ::: "memory");
  __builtin_amdgcn_s_barrier();
  __builtin_amdgcn_sched_barrier(0);

  for (int i = 0; i < NI; i++) {
    int t0 = 2 * i, t1 = 2 * i + 1;
    // ---- K-tile t0 (dbuf0) ----
    // p0
    ldA(0, 0); ldB2(0, 0);
    stage(0, t1, 0);          // A(t1)h0
    mfma_q(0, 0);
    // p1
    ldB2(0, 1);
    stage(0, t1, 1);          // A(t1)h1
    mfma_q(0, 1);
    // p2
    ldA(0, 1);
    stage(1, t0 + 2, 0);      // B(t0+2)h0
    mfma_q(1, 0);
    // p3
    stage(1, t0 + 2, 1);      // B(t0+2)h1
    mfma_q(1, 1);
    // ---- boundary: tile t1 data (B staged prev p6/p7, A staged this p0/p1) ready ----
    asm volatile("s_waitcnt vmcnt(4)" ::: "memory");
    __builtin_amdgcn_s_barrier();
    __builtin_amdgcn_sched_barrier(0);
    // ---- K-tile t1 (dbuf1) ----
    // p4
    ldA(1, 0); ldB2(1, 0);
    stage(0, t0 + 2, 0);      // A(t0+2)h0
    mfma_q(0, 0);
    // p5
    ldB2(1, 1);
    stage(0, t0 + 2, 1);      // A(t0+2)h1
    mfma_q(0, 1);
    // p6
    ldA(1, 1);
    stage(1, t1 + 2, 0);      // B(t1+2)h0
    mfma_q(1, 0);
    // p7
    stage(1, t1 + 2, 1);      // B(t1+2)h1
    mfma_q(1, 1);
    // ---- end-of-iter boundary: tile t0+2 (staged p2..p5) ready; B(t1+2) stays in flight ----
    asm volatile("s_waitcnt vmcnt(4)" ::: "memory");
    __builtin_amdgcn_s_barrier();
    __builtin_amdgcn_sched_barrier(0);
  }

  // epilogue
#pragma unroll
  for (int m = 0; m < 8; m++) {
    int row = bm * 256 + wm * 128 + m * 16 + g * 4;
    if (EPI == 0) {
#pragma unroll
      for (int n = 0; n < 4; n++) {
        int col = bn * 256 + wn * 64 + n * 16 + l15;
#pragma unroll
        for (int r = 0; r < 4; r++) outF[(size_t)(row + r) * N + col] = acc[m][n][r];
      }
    } else {
#pragma unroll
      for (int n = 0; n < 4; n += 2) {
        int np = bn * 256 + wn * 64 + n * 16 + l15;
        int j = ((np >> 5) << 4) | (np & 15);
        float bx = bias[j], bg = bias[j + 4096];
#pragma unroll
        for (int r = 0; r < 4; r++) {
          float xh = acc[m][n][r] + bx;
          float gt = acc[m][n + 1][r] + bg;
          float v = gt / (1.0f + __expf(-gt)) * xh;
          outB[(size_t)(row + r) * 5120 + j] = f2bf(v);
        }
      }
    }
  }
}

// ============ deep-pipelined 128x128 GEMM, BK=32, 3-stage pipeline, 4 waves ============
// final: out = A(AB,stride=K=5120) x Btc^T + bffout + bo + lam*h
__global__ __launch_bounds__(256, 3) void gemm128f(const bfu* __restrict__ A, const bfu* __restrict__ Bt,
                                                   float* __restrict__ out,
                                                   const float* __restrict__ b1,
                                                   const float* __restrict__ b2,
                                                   const float* __restrict__ lam,
                                                   const float* __restrict__ h,
                                                   int M, int N, int K) {
  __shared__ __align__(16) char lds[49152];  // 3 x (A 8KB | B 8KB)
  int nbx = N >> 7;
  int nwg = gridDim.x;
  int id = blockIdx.x;
  { int q = nwg >> 3; id = (id & 7) * q + (id >> 3); }
  int bm = id / nbx, bn = id % nbx;
  int tid = threadIdx.x, w = tid >> 6, lane = tid & 63;
  int wm = w >> 1, wn = w & 1;
  int g = lane >> 4, l15 = lane & 15;
  int NT = K >> 5;

  f32x4 acc[4][4];
#pragma unroll
  for (int m = 0; m < 4; m++)
#pragma unroll
    for (int n = 0; n < 4; n++) acc[m][n] = (f32x4){0.f, 0.f, 0.f, 0.f};

  auto stage = [&](int buf, int t) {
    int k0 = t << 5;
#pragma unroll
    for (int r = 0; r < 2; r++) {
      int L = r * 256 + tid;
      int row = L >> 2, c = L & 3;
      int kc = c ^ (row & 3);
      const bfu* srcA = A + (size_t)(bm * 128 + row) * K + k0 + kc * 8;
      char* dstA = lds + buf * 16384 + r * 4096 + w * 1024;
      __builtin_amdgcn_global_load_lds((AS1q)srcA, (AS3q)dstA, 16, 0, 0);
      const bfu* srcB = Bt + (size_t)(bn * 128 + row) * K + k0 + kc * 8;
      char* dstB = lds + buf * 16384 + 8192 + r * 4096 + w * 1024;
      __builtin_amdgcn_global_load_lds((AS1q)srcB, (AS3q)dstB, 16, 0, 0);
    }
  };

  stage(0, 0); stage(1, 1);
  asm volatile("s_waitcnt vmcnt(4)" ::: "memory");
  __builtin_amdgcn_s_barrier();
  __builtin_amdgcn_sched_barrier(0);

  int bc = 0;
  for (int t = 0; t < NT; t++) {
    int bs = bc + 2; if (bs >= 3) bs -= 3;
    if (t + 2 < NT) stage(bs, t + 2);
    const char* la = lds + bc * 16384;
    const char* lb = la + 8192;
    s16x8 af[4], bfr[4];
#pragma unroll
    for (int m = 0; m < 4; m++) {
      int row = wm * 64 + m * 16 + l15;
      af[m] = *reinterpret_cast<const s16x8*>(la + row * 64 + ((g ^ (row & 3)) << 4));
    }
#pragma unroll
    for (int n = 0; n < 4; n++) {
      int row = wn * 64 + n * 16 + l15;
      bfr[n] = *reinterpret_cast<const s16x8*>(lb + row * 64 + ((g ^ (row & 3)) << 4));
    }
    asm volatile("s_waitcnt lgkmcnt(0)" ::: "memory");
    __builtin_amdgcn_sched_barrier(0);
    __builtin_amdgcn_s_setprio(1);
#pragma unroll
    for (int m = 0; m < 4; m++)
#pragma unroll
      for (int n = 0; n < 4; n++)
        acc[m][n] = __builtin_amdgcn_mfma_f32_16x16x32_bf16(af[m], bfr[n], acc[m][n], 0, 0, 0);
    __builtin_amdgcn_s_setprio(0);
    __builtin_amdgcn_sched_barrier(0);
    if (t < NT - 2) { asm volatile("s_waitcnt vmcnt(4)" ::: "memory"); }
    else            { asm volatile("s_waitcnt vmcnt(0)" ::: "memory"); }
    __builtin_amdgcn_s_barrier();
    __builtin_amdgcn_sched_barrier(0);
    bc++; if (bc == 3) bc = 0;
  }

  float lv = lam[0];
#pragma unroll
  for (int m = 0; m < 4; m++) {
    int row = bm * 128 + wm * 64 + m * 16 + g * 4;
#pragma unroll
    for (int n = 0; n < 4; n++) {
      int col = bn * 128 + wn * 64 + n * 16 + l15;
      float bb = b1[col] + b2[col];
#pragma unroll
      for (int r = 0; r < 4; r++) {
        size_t o = (size_t)(row + r) * 1024 + col;
        out[o] = acc[m][n][r] + bb + lv * h[o];
      }
    }
  }
}

// ---------------- l2norm + rope, all 4 projections ----------------
__global__ __launch_bounds__(256) void ropenorm4(const float* __restrict__ raw,
                                                 const bfu* __restrict__ ct, const bfu* __restrict__ st,
                                                 bfu* __restrict__ qb, bfu* __restrict__ kb,
                                                 float* __restrict__ bqf, float* __restrict__ bkf) {
  int which = blockIdx.y;
  int colofs = (which == 0) ? 0 : (which == 1) ? 1024 : (which == 2) ? 3072 : 4096;
  int wave = threadIdx.x >> 6, lane = threadIdx.x & 63;
  int idx = blockIdx.x * 4 + wave;
  int h = idx & 15;
  int s = (idx >> 4) & 1023;
  int b = idx >> 14;
  size_t rowi = (size_t)(idx >> 4);
  float x = raw[rowi * 5120 + colofs + (h << 6) + lane];
  float ss = x * x;
#pragma unroll
  for (int m = 1; m < 64; m <<= 1) ss += __shfl_xor(ss, m);
  float nrm = sqrtf(ss);
  float xn = x / fmaxf(nrm, 1e-12f);
  float part = __shfl_xor(xn, 32);
  int pi = lane & 31;
  float c = bf2f(ct[(s << 5) + pi]);
  float sn = bf2f(st[(s << 5) + pi]);
  float outv = (lane < 32) ? (xn * c + part * sn) : (xn * c - part * sn);
  size_t dofs = ((size_t)((b << 4) + h) * 1024 + s) * 64 + lane;
  if (which == 0) qb[dofs] = f2bf(outv);
  else if (which == 1) kb[dofs] = f2bf(outv);
  else if (which == 2) bqf[dofs] = outv;
  else bkf[dofs] = outv;
}

// ---------------- v transpose ----------------
__global__ __launch_bounds__(256) void vtrans(const float* __restrict__ raw, bfu* __restrict__ vT) {
  __shared__ float t[64][65];
  int bh = blockIdx.y, stile = blockIdx.x;
  int b = bh >> 4, h = bh & 15;
  int s0 = stile << 6;
  for (int ii = threadIdx.x; ii < 4096; ii += 256) {
    int r = ii >> 6, d = ii & 63;
    t[r][d] = raw[(size_t)(b * 1024 + s0 + r) * 5120 + (h << 6) + d];
  }
  __syncthreads();
  for (int ii = threadIdx.x; ii < 4096; ii += 256) {
    int d = ii >> 6, sc = ii & 63;
    vT[((size_t)(bh * 64 + d) << 10) + s0 + sc] = f2bf(t[sc][d]);
  }
}

// ---------------- brow ----------------
__global__ void bk_chunksum(const float* __restrict__ bk, float* __restrict__ csum) {
  int cid = blockIdx.x;
  int bh = cid >> 3, c = cid & 7, lane = threadIdx.x;
  float s = 0.f;
  const float* p = bk + ((size_t)bh * 1024 + c * 128) * 64 + lane;
  for (int j = 0; j < 128; j++) s += p[(size_t)j * 64];
  csum[cid * 64 + lane] = s;
}

__global__ void brow_k(const float* __restrict__ bq, const float* __restrict__ bk,
                       const float* __restrict__ csum, float* __restrict__ brow) {
  int cid = blockIdx.x;
  int bh = cid >> 3, c = cid & 7, lane = threadIdx.x;
  float p = 0.f;
  for (int cc = 0; cc < c; cc++) p += csum[(bh * 8 + cc) * 64 + lane];
  size_t base = ((size_t)bh * 1024 + c * 128) * 64 + lane;
  for (int j = 0; j < 128; j++) {
    p += bk[base + (size_t)j * 64];
    float t = bq[base + (size_t)j * 64] * p;
#pragma unroll
    for (int m2 = 1; m2 < 64; m2 <<= 1) t += __shfl_xor(t, m2);
    if (lane == 0) brow[bh * 1024 + c * 128 + j] = 0.125f * t;
  }
}

// ---------------- flash attention (writes y into AB cols 4096.. stride 5120) ----------------
__global__ __launch_bounds__(256) void flash_k(const bfu* __restrict__ q, const bfu* __restrict__ k,
                                               const bfu* __restrict__ vT,
                                               const float* __restrict__ brow,
                                               const float* __restrict__ l2p,
                                               bfu* __restrict__ y) {
  __shared__ __align__(16) bfu P[4][2][16][72];
  int id = blockIdx.x;  // 0..511
  int sub = id & 255;
  int qt = (id >> 8) ? 7 - (sub >> 6) : (sub >> 6);
  int bh = sub & 63;
  int wave = threadIdx.x >> 6, lane = threadIdx.x & 63;
  int g = lane >> 4, l15 = lane & 15;
  const size_t bhofs = (size_t)bh << 16;
  int rt0 = qt * 128 + wave * 32;

  s16x8 aq[2][2];
#pragma unroll
  for (int m = 0; m < 2; m++)
#pragma unroll
    for (int ks = 0; ks < 2; ks++)
      aq[m][ks] = *reinterpret_cast<const s16x8*>(
          q + bhofs + (size_t)(rt0 + m * 16 + l15) * 64 + ks * 32 + g * 8);

  f32x4 O[2][4];
  float mr[2][4], lr[2][4];
#pragma unroll
  for (int m = 0; m < 2; m++)
#pragma unroll
    for (int r = 0; r < 4; r++) { O[m][r] = (f32x4){0.f, 0.f, 0.f, 0.f}; mr[m][r] = -3.0e38f; lr[m][r] = 0.f; }

  s16x8 kA[4][2], kB[4][2];
  auto loadK = [&](s16x8 (&kd)[4][2], int jt) {
#pragma unroll
    for (int nt = 0; nt < 4; nt++)
#pragma unroll
      for (int ks = 0; ks < 2; ks++)
        kd[nt][ks] = *reinterpret_cast<const s16x8*>(
            k + bhofs + (size_t)(jt * 64 + nt * 16 + l15) * 64 + ks * 32 + g * 8);
  };

  int njt = 2 * qt + 2;
  loadK(kA, 0);

  auto body = [&](int jt, s16x8 (&kc)[4][2], s16x8 (&kn)[4][2], bool pf) {
    s16x8 vv[4][2];
#pragma unroll
    for (int nt = 0; nt < 4; nt++)
#pragma unroll
      for (int ks = 0; ks < 2; ks++)
        vv[nt][ks] = *reinterpret_cast<const s16x8*>(
            vT + ((size_t)(bh * 64 + nt * 16 + l15) << 10) + jt * 64 + ks * 32 + g * 8);

    bool act[2] = { jt * 64 <= rt0 + 15, jt * 64 <= rt0 + 31 };
    f32x4 sfr[2][4];
#pragma unroll
    for (int m = 0; m < 2; m++) {
      if (!act[m]) continue;
#pragma unroll
      for (int nt = 0; nt < 4; nt++) {
        sfr[m][nt] = (f32x4){0.f, 0.f, 0.f, 0.f};
#pragma unroll
        for (int ks = 0; ks < 2; ks++)
          sfr[m][nt] = __builtin_amdgcn_mfma_f32_16x16x32_bf16(aq[m][ks], kc[nt][ks], sfr[m][nt], 0, 0, 0);
      }
    }
    if (pf) loadK(kn, jt + 1);

#pragma unroll
    for (int m = 0; m < 2; m++) {
      if (!act[m]) continue;
      int rtm = rt0 + m * 16;
      if (jt * 64 + 63 > rtm) {
#pragma unroll
        for (int ntn = 0; ntn < 4; ntn++)
#pragma unroll
          for (int r = 0; r < 4; r++)
            if (jt * 64 + ntn * 16 + l15 > rtm + g * 4 + r) sfr[m][ntn][r] = -1e30f;
      }
      float alpha[4];
#pragma unroll
      for (int r = 0; r < 4; r++) {
        float v = fmaxf(fmaxf(sfr[m][0][r], sfr[m][1][r]), fmaxf(sfr[m][2][r], sfr[m][3][r]));
#pragma unroll
        for (int m2 = 1; m2 < 16; m2 <<= 1) v = fmaxf(v, __shfl_xor(v, m2));
        float mn = fmaxf(mr[m][r], v);
        alpha[r] = __expf(mr[m][r] - mn);
        mr[m][r] = mn;
      }
#pragma unroll
      for (int r = 0; r < 4; r++) {
        float rs = 0.f;
#pragma unroll
        for (int ntn = 0; ntn < 4; ntn++) {
          float e = __expf(sfr[m][ntn][r] - mr[m][r]);
          rs += e;
          P[wave][m][g * 4 + r][ntn * 16 + l15] = f2bf(e);
        }
#pragma unroll
        for (int m2 = 1; m2 < 16; m2 <<= 1) rs += __shfl_xor(rs, m2);
        lr[m][r] = lr[m][r] * alpha[r] + rs;
#pragma unroll
        for (int ntn = 0; ntn < 4; ntn++) O[m][ntn][r] *= alpha[r];
      }
    }
    asm volatile("s_waitcnt lgkmcnt(0)" ::: "memory");
    __builtin_amdgcn_sched_barrier(0);
#pragma unroll
    for (int m = 0; m < 2; m++) {
      if (!act[m]) continue;
      s16x8 pa[2];
#pragma unroll
      for (int ks = 0; ks < 2; ks++)
        pa[ks] = *reinterpret_cast<const s16x8*>(&P[wave][m][l15][ks * 32 + g * 8]);
#pragma unroll
      for (int nt = 0; nt < 4; nt++)
#pragma unroll
        for (int ks = 0; ks < 2; ks++)
          O[m][nt] = __builtin_amdgcn_mfma_f32_16x16x32_bf16(pa[ks], vv[nt][ks], O[m][nt], 0, 0, 0);
    }
  };

  for (int jt = 0; jt < njt; jt += 2) {
    body(jt, kA, kB, true);
    body(jt + 1, kB, kA, jt + 2 < njt);
  }

  float l2ns = l2p[0];
  int b = bh >> 4, h = bh & 15;
#pragma unroll
  for (int m = 0; m < 2; m++)
#pragma unroll
    for (int nt = 0; nt < 4; nt++)
#pragma unroll
      for (int r = 0; r < 4; r++) {
        int rowg = rt0 + m * 16 + g * 4 + r;
        float val = O[m][nt][r] * (l2ns / lr[m][r]) + brow[bh * 1024 + rowg];
        y[(size_t)(b * 1024 + rowg) * 5120 + 4096 + h * 64 + nt * 16 + l15] = f2bf(val);
      }
}

// ================= host =================
extern "C" void kernel_launch(void* const* d_in, const int* in_sizes, int n_in,
                              void* d_out, int out_size, void* d_ws, size_t ws_size,
                              hipStream_t stream) {
  const float* h      = (const float*)d_in[0];
  const float* Wq     = (const float*)d_in[2];
  const float* Wk     = (const float*)d_in[3];
  const float* Wv     = (const float*)d_in[4];
  const float* WqB    = (const float*)d_in[5];
  const float* WkB    = (const float*)d_in[6];
  const float* Wo     = (const float*)d_in[7];
  const float* bo     = (const float*)d_in[8];
  const float* Wffin  = (const float*)d_in[9];
  const float* bffin  = (const float*)d_in[10];
  const float* Wffout = (const float*)d_in[11];
  const float* bffout = (const float*)d_in[12];
  const float* lam    = (const float*)d_in[13];
  const float* l2ns   = (const float*)d_in[14];
  float* out = (float*)d_out;

  char* ws = (char*)d_ws;
  size_t off = 0;
  auto alloc = [&](size_t bytes) { void* p = ws + off; off += bytes; return p; };
  bfu* wt5   = (bfu*)alloc(5ull * 1024 * 1024 * 2);   // [5120][1024]
  bfu* wtfi  = (bfu*)alloc(8192ull * 1024 * 2);       // [8192][1024] (perm rows)
  bfu* wtfoc = (bfu*)alloc(1024ull * 5120 * 2);       // [1024][5120] = Wffout_t | Wo_t
  bfu* cosb  = (bfu*)alloc(1024ull * 32 * 2);
  bfu* sinb  = (bfu*)alloc(1024ull * 32 * 2);
  bfu* inner = (bfu*)alloc(4096ull * 1024 * 2);
  bfu* qb    = (bfu*)alloc(64ull * 1024 * 64 * 2);
  bfu* kb    = (bfu*)alloc(64ull * 1024 * 64 * 2);
  bfu* vtb   = (bfu*)alloc(64ull * 1024 * 64 * 2);
  float* bqf = (float*)alloc(64ull * 1024 * 64 * 4);
  float* bkf = (float*)alloc(64ull * 1024 * 64 * 4);
  float* csum  = (float*)alloc(64ull * 8 * 64 * 4);
  float* browb = (float*)alloc(64ull * 1024 * 4);
  float* raw = (float*)alloc(4096ull * 5120 * 4);     // 80MB; AB overlays it
  bfu* AB    = (bfu*)raw;                             // [4096][5120] bf16: act | y

  // weights
  Ptr5 p5; p5.p[0] = Wq; p5.p[1] = Wk; p5.p[2] = Wv; p5.p[3] = WqB; p5.p[4] = WkB;
  wconv5<<<dim3(32, 32, 5), 256, 0, stream>>>(p5, wt5);
  wconv_t<1><<<dim3(256, 32), 256, 0, stream>>>(Wffin, wtfi, 1024, 8192, 1024, 0);
  wconv_t<0><<<dim3(32, 128), 256, 0, stream>>>(Wffout, wtfoc, 4096, 1024, 5120, 0);
  wconv_t<0><<<dim3(32, 32), 256, 0, stream>>>(Wo, wtfoc, 1024, 1024, 5120, 4096);
  rope_tab<<<128, 256, 0, stream>>>(cosb, sinb);
  rmsnorm_k<<<4096, 256, 0, stream>>>(h, inner);

  // fused 5-way projection -> raw [4096][5120] f32
  gemm256p<0><<<dim3(16 * 20), 512, 0, stream>>>(inner, wt5, raw, nullptr, nullptr, 4096, 5120, 1024);

  ropenorm4<<<dim3(16384, 4), 256, 0, stream>>>(raw, cosb, sinb, qb, kb, bqf, bkf);
  vtrans<<<dim3(16, 64), 256, 0, stream>>>(raw + 2048, vtb);

  bk_chunksum<<<512, 64, 0, stream>>>(bkf, csum);
  brow_k<<<512, 64, 0, stream>>>(bqf, bkf, csum, browb);

  // flash writes y into AB cols 4096.. (raw is dead after ropenorm4+vtrans)
  flash_k<<<dim3(512), 256, 0, stream>>>(qb, kb, vtb, browb, l2ns, AB);

  // FF-in + silu fused -> AB cols 0..4095
  gemm256p<1><<<dim3(16 * 32), 512, 0, stream>>>(inner, wtfi, nullptr, AB, bffin, 4096, 8192, 1024);

  // final merged: out = AB @ [Wffout|Wo]^T + bffout + bo + lam*h
  gemm128f<<<dim3(32 * 8), 256, 0, stream>>>(AB, wtfoc, out, bffout, bo, lam, h, 4096, 1024, 5120);
}

// Round 5
// 377.316 us; speedup vs baseline: 1.4763x; 1.0746x over previous
//
#include <hip/hip_runtime.h>
#include <stdint.h>
#include <math.h>

typedef float f32x4 __attribute__((ext_vector_type(4)));
typedef short s16x8 __attribute__((ext_vector_type(8)));
typedef unsigned short bfu;

#define AS1q const __attribute__((address_space(1))) void*
#define AS3q __attribute__((address_space(3))) void*

static __device__ __forceinline__ float bf2f(bfu v) {
  return __uint_as_float(((unsigned int)v) << 16);
}
static __device__ __forceinline__ bfu f2bf(float f) {
  unsigned int u = __float_as_uint(f);
  return (bfu)((u + 0x7fffu + ((u >> 16) & 1u)) >> 16);
}

// ---------------- weight convert + transpose ----------------
// MODE 0: Wt[n*dstride + dofs + k] = bf16(W[k][n])
// MODE 1 (ffin perm): n' = ((j>>4)<<5) | (isgate<<4) | (j&15), j=n&4095
template <int MODE>
__global__ __launch_bounds__(256) void wconv_t(const float* __restrict__ W, bfu* __restrict__ Wt,
                                               int K, int N, int dstride, int dofs) {
  __shared__ float t[32][33];
  int tx = threadIdx.x & 31, ty = threadIdx.x >> 5;
  int nb = blockIdx.x * 32, kb = blockIdx.y * 32;
#pragma unroll
  for (int i = 0; i < 4; i++) {
    int r = ty + i * 8;
    t[r][tx] = W[(size_t)(kb + r) * N + nb + tx];
  }
  __syncthreads();
#pragma unroll
  for (int i = 0; i < 4; i++) {
    int r = ty + i * 8;
    int n = nb + r;
    int nd;
    if (MODE == 1) {
      int j = n & 4095, isg = n >> 12;
      nd = ((j >> 4) << 5) | (isg << 4) | (j & 15);
    } else nd = n;
    Wt[(size_t)nd * dstride + dofs + kb + tx] = f2bf(t[tx][r]);
  }
}

// batched 1024x1024 weight conversions (5 weights in one launch)
struct Ptr5 { const float* p[5]; };
__global__ __launch_bounds__(256) void wconv5(Ptr5 srcs, bfu* __restrict__ dst) {
  __shared__ float t[32][33];
  const float* W = srcs.p[blockIdx.z];
  bfu* Wt = dst + ((size_t)blockIdx.z << 20);
  int tx = threadIdx.x & 31, ty = threadIdx.x >> 5;
  int nb = blockIdx.x * 32, kb = blockIdx.y * 32;
#pragma unroll
  for (int i = 0; i < 4; i++) {
    int r = ty + i * 8;
    t[r][tx] = W[(size_t)(kb + r) * 1024 + nb + tx];
  }
  __syncthreads();
#pragma unroll
  for (int i = 0; i < 4; i++) {
    int r = ty + i * 8;
    Wt[(size_t)(nb + r) * 1024 + kb + tx] = f2bf(t[tx][r]);
  }
}

// ---------------- rope tables ----------------
__global__ void rope_tab(bfu* __restrict__ ct, bfu* __restrict__ st) {
  int idx = blockIdx.x * 256 + threadIdx.x;  // 1024*32
  int s = idx >> 5, i = idx & 31;
  float f = powf(1000.0f, -(float)i / 32.0f);
  float fr = (float)s * f;
  ct[idx] = f2bf(cosf(fr));
  st[idx] = f2bf(sinf(fr));
}

// ---------------- rmsnorm ----------------
__global__ __launch_bounds__(256) void rmsnorm_k(const float* __restrict__ h, bfu* __restrict__ inner) {
  int row = blockIdx.x;
  const float* hr = h + (size_t)row * 1024;
  f32x4 x = *reinterpret_cast<const f32x4*>(hr + threadIdx.x * 4);
  float ss = x[0] * x[0] + x[1] * x[1] + x[2] * x[2] + x[3] * x[3];
  for (int off = 32; off; off >>= 1) ss += __shfl_down(ss, off);
  __shared__ float wsum[4];
  int wave = threadIdx.x >> 6, lane = threadIdx.x & 63;
  if (lane == 0) wsum[wave] = ss;
  __syncthreads();
  float tot = wsum[0] + wsum[1] + wsum[2] + wsum[3];
  float r = rsqrtf(tot * (1.0f / 1024.0f) + 1.1920929e-07f);
  bfu* o = inner + (size_t)row * 1024 + threadIdx.x * 4;
  o[0] = f2bf(x[0] * r); o[1] = f2bf(x[1] * r);
  o[2] = f2bf(x[2] * r); o[3] = f2bf(x[3] * r);
}

// ============ 8-phase 256x256 GEMM, BK=64, 2-dbuf LDS, counted vmcnt ============
// EPI 1: silu-fused -> outB bf16 stride 5120 (FF-in)
// EPI 2: proj-fused -> l2norm+rope -> qb/kb bf16, vb bf16 plain, bqf/bkf f32
// grid = 8 * rbm * rbn; XCD c owns rect rbm x rbn of tiles (L2 locality)
template <int EPI>
__global__ __launch_bounds__(512, 2) void gemm256p(const bfu* __restrict__ A, const bfu* __restrict__ Bt,
                                                   bfu* __restrict__ outB,
                                                   const float* __restrict__ bias,
                                                   bfu* __restrict__ qb, bfu* __restrict__ kb,
                                                   bfu* __restrict__ vb,
                                                   float* __restrict__ bqf, float* __restrict__ bkf,
                                                   const bfu* __restrict__ ct, const bfu* __restrict__ st,
                                                   int M, int N, int K, int rbm, int rbn) {
  __shared__ __align__(16) char lds[131072];
  int nbx = N >> 8;
  int c = blockIdx.x & 7, rr = blockIdx.x >> 3;   // XCD chunk, index within rect
  int ca = nbx / rbn;
  int bn0 = (c % ca) * rbn, bm0 = (c / ca) * rbm;
  int bm = bm0 + rr / rbn, bn = bn0 + rr % rbn;
  int tid = threadIdx.x, w = tid >> 6, lane = tid & 63;
  int wm = w >> 2, wn = w & 3;
  int g = lane >> 4, l15 = lane & 15;
  int NT = K >> 6;   // BK=64 tiles (must be even)
  int NI = NT >> 1;

  f32x4 acc[8][4];
#pragma unroll
  for (int m = 0; m < 8; m++)
#pragma unroll
    for (int n = 0; n < 4; n++) acc[m][n] = (f32x4){0.f, 0.f, 0.f, 0.f};

  s16x8 af[4][2];   // current quadrant A frags (4 m x 2 ks)
  s16x8 bfr[4][2];  // all 4 n-frags of wave's 64-col strip

  // stage one half-tile (2 global_load_lds / thread). mat 0=A 1=B.
  auto stage = [&](int mat, int kt, int hf) {
    if (kt >= NT) return;
    int d = kt & 1;
    const bfu* s0 = (mat == 0) ? A : Bt;
    int rowbase = ((mat == 0) ? bm : bn) * 256 + hf * 128;
    int k0 = kt << 6;
    char* base = lds + d * 65536 + mat * 32768 + hf * 16384;
#pragma unroll
    for (int r = 0; r < 2; r++) {
      int L = r * 512 + tid;
      int row = L >> 3, cc = L & 7;
      int kc = cc ^ (row & 7);
      const bfu* src = s0 + (size_t)(rowbase + row) * K + k0 + kc * 8;
      char* dst = base + r * 8192 + w * 1024;
      __builtin_amdgcn_global_load_lds((AS1q)src, (AS3q)dst, 16, 0, 0);
    }
  };

  auto ldA = [&](int d, int mh) {
    const char* base = lds + d * 65536 + wm * 16384;
#pragma unroll
    for (int mm = 0; mm < 4; mm++) {
      int row = mh * 64 + mm * 16 + l15;
#pragma unroll
      for (int ks = 0; ks < 2; ks++)
        af[mm][ks] = *reinterpret_cast<const s16x8*>(
            base + row * 128 + (((ks * 4 + g) ^ (row & 7)) << 4));
    }
  };
  auto ldB2 = [&](int d, int nh) {
    const char* base = lds + d * 65536 + 32768 + (wn >> 1) * 16384;
#pragma unroll
    for (int nn = 0; nn < 2; nn++) {
      int row = (wn & 1) * 64 + (nh * 2 + nn) * 16 + l15;
#pragma unroll
      for (int ks = 0; ks < 2; ks++)
        bfr[nh * 2 + nn][ks] = *reinterpret_cast<const s16x8*>(
            base + row * 128 + (((ks * 4 + g) ^ (row & 7)) << 4));
    }
  };
  auto mfma_q = [&](int mh, int nh) {
    asm volatile("s_waitcnt lgkmcnt(0)" ::: "memory");
    __builtin_amdgcn_sched_barrier(0);
    __builtin_amdgcn_s_barrier();
    __builtin_amdgcn_s_setprio(1);
#pragma unroll
    for (int mm = 0; mm < 4; mm++)
#pragma unroll
      for (int nn = 0; nn < 2; nn++) {
        int n = nh * 2 + nn, m = mh * 4 + mm;
#pragma unroll
        for (int ks = 0; ks < 2; ks++)
          acc[m][n] = __builtin_amdgcn_mfma_f32_16x16x32_bf16(af[mm][ks], bfr[n][ks], acc[m][n], 0, 0, 0);
      }
    __builtin_amdgcn_s_setprio(0);
    __builtin_amdgcn_sched_barrier(0);
  };

  // prologue: tile 0 (all 4 halves) + B(1) both halves; leave B(1) in flight
  stage(1, 0, 0); stage(0, 0, 0); stage(0, 0, 1); stage(1, 0, 1);
  stage(1, 1, 0); stage(1, 1, 1);
  asm volatile("s_waitcnt vmcnt(4)" ::: "memory");
  __builtin_amdgcn_s_barrier();
  __builtin_amdgcn_sched_barrier(0);

  for (int i = 0; i < NI; i++) {
    int t0 = 2 * i, t1 = 2 * i + 1;
    // ---- K-tile t0 (dbuf0) ----
    ldA(0, 0); ldB2(0, 0);
    stage(0, t1, 0);          // A(t1)h0
    mfma_q(0, 0);
    ldB2(0, 1);
    stage(0, t1, 1);          // A(t1)h1
    mfma_q(0, 1);
    ldA(0, 1);
    stage(1, t0 + 2, 0);      // B(t0+2)h0
    mfma_q(1, 0);
    stage(1, t0 + 2, 1);      // B(t0+2)h1
    mfma_q(1, 1);
    asm volatile("s_waitcnt vmcnt(4)" ::: "memory");
    __builtin_amdgcn_s_barrier();
    __builtin_amdgcn_sched_barrier(0);
    // ---- K-tile t1 (dbuf1) ----
    ldA(1, 0); ldB2(1, 0);
    stage(0, t0 + 2, 0);      // A(t0+2)h0
    mfma_q(0, 0);
    ldB2(1, 1);
    stage(0, t0 + 2, 1);      // A(t0+2)h1
    mfma_q(0, 1);
    ldA(1, 1);
    stage(1, t1 + 2, 0);      // B(t1+2)h0
    mfma_q(1, 0);
    stage(1, t1 + 2, 1);      // B(t1+2)h1
    mfma_q(1, 1);
    asm volatile("s_waitcnt vmcnt(4)" ::: "memory");
    __builtin_amdgcn_s_barrier();
    __builtin_amdgcn_sched_barrier(0);
  }

  // ================= epilogue =================
  if (EPI == 1) {
#pragma unroll
    for (int m = 0; m < 8; m++) {
      int row = bm * 256 + wm * 128 + m * 16 + g * 4;
#pragma unroll
      for (int n = 0; n < 4; n += 2) {
        int np = bn * 256 + wn * 64 + n * 16 + l15;
        int j = ((np >> 5) << 4) | (np & 15);
        float bx = bias[j], bg = bias[j + 4096];
#pragma unroll
        for (int r = 0; r < 4; r++) {
          float xh = acc[m][n][r] + bx;
          float gt = acc[m][n + 1][r] + bg;
          float v = gt / (1.0f + __expf(-gt)) * xh;
          outB[(size_t)(row + r) * 5120 + j] = f2bf(v);
        }
      }
    }
  } else {
    // proj: bn 0-3 q | 4-7 k | 8-11 v | 12-15 bq | 16-19 bk; wave strip = one head
    int which = bn >> 2;
    int hh = (bn & 3) * 4 + wn;
    if (which == 2) {
#pragma unroll
      for (int m = 0; m < 8; m++)
#pragma unroll
        for (int r = 0; r < 4; r++) {
          int row = bm * 256 + wm * 128 + m * 16 + g * 4 + r;
#pragma unroll
          for (int n = 0; n < 4; n++)
            vb[(size_t)row * 1024 + hh * 64 + n * 16 + l15] = f2bf(acc[m][n][r]);
        }
    } else {
#pragma unroll
      for (int m = 0; m < 8; m++) {
#pragma unroll
        for (int r = 0; r < 4; r++) {
          int row = bm * 256 + wm * 128 + m * 16 + g * 4 + r;
          int s = row & 1023, b = row >> 10;
          float ss = 0.f;
#pragma unroll
          for (int n = 0; n < 4; n++) ss += acc[m][n][r] * acc[m][n][r];
          ss += __shfl_xor(ss, 1); ss += __shfl_xor(ss, 2);
          ss += __shfl_xor(ss, 4); ss += __shfl_xor(ss, 8);
          float inv = 1.0f / fmaxf(sqrtf(ss), 1e-12f);
          float xn0 = acc[m][0][r] * inv, xn1 = acc[m][1][r] * inv;
          float xn2 = acc[m][2][r] * inv, xn3 = acc[m][3][r] * inv;
          float c0 = bf2f(ct[(s << 5) + l15]),      s0v = bf2f(st[(s << 5) + l15]);
          float c1 = bf2f(ct[(s << 5) + 16 + l15]), s1v = bf2f(st[(s << 5) + 16 + l15]);
          float o0 = xn0 * c0 + xn2 * s0v;
          float o1 = xn1 * c1 + xn3 * s1v;
          float o2 = xn2 * c0 - xn0 * s0v;
          float o3 = xn3 * c1 - xn1 * s1v;
          size_t base = (((size_t)((b << 4) + hh) << 10) + s) << 6;
          if (which == 0) {
            qb[base + l15] = f2bf(o0); qb[base + 16 + l15] = f2bf(o1);
            qb[base + 32 + l15] = f2bf(o2); qb[base + 48 + l15] = f2bf(o3);
          } else if (which == 1) {
            kb[base + l15] = f2bf(o0); kb[base + 16 + l15] = f2bf(o1);
            kb[base + 32 + l15] = f2bf(o2); kb[base + 48 + l15] = f2bf(o3);
          } else if (which == 3) {
            bqf[base + l15] = o0; bqf[base + 16 + l15] = o1;
            bqf[base + 32 + l15] = o2; bqf[base + 48 + l15] = o3;
          } else {
            bkf[base + l15] = o0; bkf[base + 16 + l15] = o1;
            bkf[base + 32 + l15] = o2; bkf[base + 48 + l15] = o3;
          }
        }
      }
    }
  }
}

// ============ deep-pipelined 128x128 GEMM, BK=32, 3-stage pipeline, 4 waves ============
// final: out = A(AB,stride=K=5120) x Btc^T + bffout + bo + lam*h
__global__ __launch_bounds__(256, 3) void gemm128f(const bfu* __restrict__ A, const bfu* __restrict__ Bt,
                                                   float* __restrict__ out,
                                                   const float* __restrict__ b1,
                                                   const float* __restrict__ b2,
                                                   const float* __restrict__ lam,
                                                   const float* __restrict__ h,
                                                   int M, int N, int K, int rbm, int rbn) {
  __shared__ __align__(16) char lds[49152];  // 3 x (A 8KB | B 8KB)
  int nbx = N >> 7;
  int c = blockIdx.x & 7, rr = blockIdx.x >> 3;
  int ca = nbx / rbn;
  int bn0 = (c % ca) * rbn, bm0 = (c / ca) * rbm;
  int bm = bm0 + rr / rbn, bn = bn0 + rr % rbn;
  int tid = threadIdx.x, w = tid >> 6, lane = tid & 63;
  int wm = w >> 1, wn = w & 1;
  int g = lane >> 4, l15 = lane & 15;
  int NT = K >> 5;

  f32x4 acc[4][4];
#pragma unroll
  for (int m = 0; m < 4; m++)
#pragma unroll
    for (int n = 0; n < 4; n++) acc[m][n] = (f32x4){0.f, 0.f, 0.f, 0.f};

  auto stage = [&](int buf, int t) {
    int k0 = t << 5;
#pragma unroll
    for (int r = 0; r < 2; r++) {
      int L = r * 256 + tid;
      int row = L >> 2, cc = L & 3;
      int kc = cc ^ (row & 3);
      const bfu* srcA = A + (size_t)(bm * 128 + row) * K + k0 + kc * 8;
      char* dstA = lds + buf * 16384 + r * 4096 + w * 1024;
      __builtin_amdgcn_global_load_lds((AS1q)srcA, (AS3q)dstA, 16, 0, 0);
      const bfu* srcB = Bt + (size_t)(bn * 128 + row) * K + k0 + kc * 8;
      char* dstB = lds + buf * 16384 + 8192 + r * 4096 + w * 1024;
      __builtin_amdgcn_global_load_lds((AS1q)srcB, (AS3q)dstB, 16, 0, 0);
    }
  };

  stage(0, 0); stage(1, 1);
  asm volatile("s_waitcnt vmcnt(4)" ::: "memory");
  __builtin_amdgcn_s_barrier();
  __builtin_amdgcn_sched_barrier(0);

  int bc = 0;
  for (int t = 0; t < NT; t++) {
    int bs = bc + 2; if (bs >= 3) bs -= 3;
    if (t + 2 < NT) stage(bs, t + 2);
    const char* la = lds + bc * 16384;
    const char* lb = la + 8192;
    s16x8 af[4], bfr[4];
#pragma unroll
    for (int m = 0; m < 4; m++) {
      int row = wm * 64 + m * 16 + l15;
      af[m] = *reinterpret_cast<const s16x8*>(la + row * 64 + ((g ^ (row & 3)) << 4));
    }
#pragma unroll
    for (int n = 0; n < 4; n++) {
      int row = wn * 64 + n * 16 + l15;
      bfr[n] = *reinterpret_cast<const s16x8*>(lb + row * 64 + ((g ^ (row & 3)) << 4));
    }
    asm volatile("s_waitcnt lgkmcnt(0)" ::: "memory");
    __builtin_amdgcn_sched_barrier(0);
    __builtin_amdgcn_s_setprio(1);
#pragma unroll
    for (int m = 0; m < 4; m++)
#pragma unroll
      for (int n = 0; n < 4; n++)
        acc[m][n] = __builtin_amdgcn_mfma_f32_16x16x32_bf16(af[m], bfr[n], acc[m][n], 0, 0, 0);
    __builtin_amdgcn_s_setprio(0);
    __builtin_amdgcn_sched_barrier(0);
    if (t < NT - 2) { asm volatile("s_waitcnt vmcnt(4)" ::: "memory"); }
    else            { asm volatile("s_waitcnt vmcnt(0)" ::: "memory"); }
    __builtin_amdgcn_s_barrier();
    __builtin_amdgcn_sched_barrier(0);
    bc++; if (bc == 3) bc = 0;
  }

  float lv = lam[0];
#pragma unroll
  for (int m = 0; m < 4; m++) {
    int row = bm * 128 + wm * 64 + m * 16 + g * 4;
#pragma unroll
    for (int n = 0; n < 4; n++) {
      int col = bn * 128 + wn * 64 + n * 16 + l15;
      float bb = b1[col] + b2[col];
#pragma unroll
      for (int r = 0; r < 4; r++) {
        size_t o = (size_t)(row + r) * 1024 + col;
        out[o] = acc[m][n][r] + bb + lv * h[o];
      }
    }
  }
}

// ---------------- v transpose: vb bf16 [b s h d] -> vT bf16 [bh][d][s] ----------------
__global__ __launch_bounds__(256) void vtrans(const bfu* __restrict__ vb, bfu* __restrict__ vT) {
  __shared__ bfu t[64][66];
  int bh = blockIdx.y, stile = blockIdx.x;
  int b = bh >> 4, h = bh & 15;
  int s0 = stile << 6;
  for (int ii = threadIdx.x; ii < 4096; ii += 256) {
    int r = ii >> 6, d = ii & 63;
    t[r][d] = vb[(size_t)(b * 1024 + s0 + r) * 1024 + (h << 6) + d];
  }
  __syncthreads();
  for (int ii = threadIdx.x; ii < 4096; ii += 256) {
    int d = ii >> 6, sc = ii & 63;
    vT[((size_t)(bh * 64 + d) << 10) + s0 + sc] = t[sc][d];
  }
}

// ---------------- brow ----------------
__global__ void bk_chunksum(const float* __restrict__ bk, float* __restrict__ csum) {
  int cid = blockIdx.x;
  int bh = cid >> 3, c = cid & 7, lane = threadIdx.x;
  float s = 0.f;
  const float* p = bk + ((size_t)bh * 1024 + c * 128) * 64 + lane;
  for (int j = 0; j < 128; j++) s += p[(size_t)j * 64];
  csum[cid * 64 + lane] = s;
}

__global__ void brow_k(const float* __restrict__ bq, const float* __restrict__ bk,
                       const float* __restrict__ csum, float* __restrict__ brow) {
  int cid = blockIdx.x;
  int bh = cid >> 3, c = cid & 7, lane = threadIdx.x;
  float p = 0.f;
  for (int cc = 0; cc < c; cc++) p += csum[(bh * 8 + cc) * 64 + lane];
  size_t base = ((size_t)bh * 1024 + c * 128) * 64 + lane;
  for (int j = 0; j < 128; j++) {
    p += bk[base + (size_t)j * 64];
    float t = bq[base + (size_t)j * 64] * p;
#pragma unroll
    for (int m2 = 1; m2 < 64; m2 <<= 1) t += __shfl_xor(t, m2);
    if (lane == 0) brow[bh * 1024 + c * 128 + j] = 0.125f * t;
  }
}

// ---------------- flash attention (writes y into AB cols 4096.. stride 5120) ----------------
__global__ __launch_bounds__(256) void flash_k(const bfu* __restrict__ q, const bfu* __restrict__ k,
                                               const bfu* __restrict__ vT,
                                               const float* __restrict__ brow,
                                               const float* __restrict__ l2p,
                                               bfu* __restrict__ y) {
  __shared__ __align__(16) bfu P[4][2][16][72];
  int id = blockIdx.x;  // 0..511
  int sub = id & 255;
  int qt = (id >> 8) ? 7 - (sub >> 6) : (sub >> 6);
  int bh = sub & 63;
  int wave = threadIdx.x >> 6, lane = threadIdx.x & 63;
  int g = lane >> 4, l15 = lane & 15;
  const size_t bhofs = (size_t)bh << 16;
  int rt0 = qt * 128 + wave * 32;

  s16x8 aq[2][2];
#pragma unroll
  for (int m = 0; m < 2; m++)
#pragma unroll
    for (int ks = 0; ks < 2; ks++)
      aq[m][ks] = *reinterpret_cast<const s16x8*>(
          q + bhofs + (size_t)(rt0 + m * 16 + l15) * 64 + ks * 32 + g * 8);

  f32x4 O[2][4];
  float mr[2][4], lr[2][4];
#pragma unroll
  for (int m = 0; m < 2; m++)
#pragma unroll
    for (int r = 0; r < 4; r++) { O[m][r] = (f32x4){0.f, 0.f, 0.f, 0.f}; mr[m][r] = -3.0e38f; lr[m][r] = 0.f; }

  s16x8 kA[4][2], kB[4][2];
  auto loadK = [&](s16x8 (&kd)[4][2], int jt) {
#pragma unroll
    for (int nt = 0; nt < 4; nt++)
#pragma unroll
      for (int ks = 0; ks < 2; ks++)
        kd[nt][ks] = *reinterpret_cast<const s16x8*>(
            k + bhofs + (size_t)(jt * 64 + nt * 16 + l15) * 64 + ks * 32 + g * 8);
  };

  int njt = 2 * qt + 2;
  loadK(kA, 0);

  auto body = [&](int jt, s16x8 (&kc)[4][2], s16x8 (&kn)[4][2], bool pf) {
    s16x8 vv[4][2];
#pragma unroll
    for (int nt = 0; nt < 4; nt++)
#pragma unroll
      for (int ks = 0; ks < 2; ks++)
        vv[nt][ks] = *reinterpret_cast<const s16x8*>(
            vT + ((size_t)(bh * 64 + nt * 16 + l15) << 10) + jt * 64 + ks * 32 + g * 8);

    bool act[2] = { jt * 64 <= rt0 + 15, jt * 64 <= rt0 + 31 };
    f32x4 sfr[2][4];
#pragma unroll
    for (int m = 0; m < 2; m++) {
      if (!act[m]) continue;
#pragma unroll
      for (int nt = 0; nt < 4; nt++) {
        sfr[m][nt] = (f32x4){0.f, 0.f, 0.f, 0.f};
#pragma unroll
        for (int ks = 0; ks < 2; ks++)
          sfr[m][nt] = __builtin_amdgcn_mfma_f32_16x16x32_bf16(aq[m][ks], kc[nt][ks], sfr[m][nt], 0, 0, 0);
      }
    }
    if (pf) loadK(kn, jt + 1);

#pragma unroll
    for (int m = 0; m < 2; m++) {
      if (!act[m]) continue;
      int rtm = rt0 + m * 16;
      if (jt * 64 + 63 > rtm) {
#pragma unroll
        for (int ntn = 0; ntn < 4; ntn++)
#pragma unroll
          for (int r = 0; r < 4; r++)
            if (jt * 64 + ntn * 16 + l15 > rtm + g * 4 + r) sfr[m][ntn][r] = -1e30f;
      }
      float alpha[4];
#pragma unroll
      for (int r = 0; r < 4; r++) {
        float v = fmaxf(fmaxf(sfr[m][0][r], sfr[m][1][r]), fmaxf(sfr[m][2][r], sfr[m][3][r]));
#pragma unroll
        for (int m2 = 1; m2 < 16; m2 <<= 1) v = fmaxf(v, __shfl_xor(v, m2));
        float mn = fmaxf(mr[m][r], v);
        alpha[r] = __expf(mr[m][r] - mn);
        mr[m][r] = mn;
      }
#pragma unroll
      for (int r = 0; r < 4; r++) {
        float rs = 0.f;
#pragma unroll
        for (int ntn = 0; ntn < 4; ntn++) {
          float e = __expf(sfr[m][ntn][r] - mr[m][r]);
          rs += e;
          P[wave][m][g * 4 + r][ntn * 16 + l15] = f2bf(e);
        }
#pragma unroll
        for (int m2 = 1; m2 < 16; m2 <<= 1) rs += __shfl_xor(rs, m2);
        lr[m][r] = lr[m][r] * alpha[r] + rs;
#pragma unroll
        for (int ntn = 0; ntn < 4; ntn++) O[m][ntn][r] *= alpha[r];
      }
    }
    asm volatile("s_waitcnt lgkmcnt(0)" ::: "memory");
    __builtin_amdgcn_sched_barrier(0);
#pragma unroll
    for (int m = 0; m < 2; m++) {
      if (!act[m]) continue;
      s16x8 pa[2];
#pragma unroll
      for (int ks = 0; ks < 2; ks++)
        pa[ks] = *reinterpret_cast<const s16x8*>(&P[wave][m][l15][ks * 32 + g * 8]);
#pragma unroll
      for (int nt = 0; nt < 4; nt++)
#pragma unroll
        for (int ks = 0; ks < 2; ks++)
          O[m][nt] = __builtin_amdgcn_mfma_f32_16x16x32_bf16(pa[ks], vv[nt][ks], O[m][nt], 0, 0, 0);
    }
  };

  for (int jt = 0; jt < njt; jt += 2) {
    body(jt, kA, kB, true);
    body(jt + 1, kB, kA, jt + 2 < njt);
  }

  float l2ns = l2p[0];
  int b = bh >> 4, h = bh & 15;
#pragma unroll
  for (int m = 0; m < 2; m++)
#pragma unroll
    for (int nt = 0; nt < 4; nt++)
#pragma unroll
      for (int r = 0; r < 4; r++) {
        int rowg = rt0 + m * 16 + g * 4 + r;
        float val = O[m][nt][r] * (l2ns / lr[m][r]) + brow[bh * 1024 + rowg];
        y[(size_t)(b * 1024 + rowg) * 5120 + 4096 + h * 64 + nt * 16 + l15] = f2bf(val);
      }
}

// ================= host =================
extern "C" void kernel_launch(void* const* d_in, const int* in_sizes, int n_in,
                              void* d_out, int out_size, void* d_ws, size_t ws_size,
                              hipStream_t stream) {
  const float* h      = (const float*)d_in[0];
  const float* Wq     = (const float*)d_in[2];
  const float* Wk     = (const float*)d_in[3];
  const float* Wv     = (const float*)d_in[4];
  const float* WqB    = (const float*)d_in[5];
  const float* WkB    = (const float*)d_in[6];
  const float* Wo     = (const float*)d_in[7];
  const float* bo     = (const float*)d_in[8];
  const float* Wffin  = (const float*)d_in[9];
  const float* bffin  = (const float*)d_in[10];
  const float* Wffout = (const float*)d_in[11];
  const float* bffout = (const float*)d_in[12];
  const float* lam    = (const float*)d_in[13];
  const float* l2ns   = (const float*)d_in[14];
  float* out = (float*)d_out;

  char* ws = (char*)d_ws;
  size_t off = 0;
  auto alloc = [&](size_t bytes) { void* p = ws + off; off += bytes; return p; };
  bfu* wt5   = (bfu*)alloc(5ull * 1024 * 1024 * 2);   // [5120][1024]
  bfu* wtfi  = (bfu*)alloc(8192ull * 1024 * 2);       // [8192][1024] (perm rows)
  bfu* wtfoc = (bfu*)alloc(1024ull * 5120 * 2);       // [1024][5120] = Wffout_t | Wo_t
  bfu* cosb  = (bfu*)alloc(1024ull * 32 * 2);
  bfu* sinb  = (bfu*)alloc(1024ull * 32 * 2);
  bfu* inner = (bfu*)alloc(4096ull * 1024 * 2);
  bfu* qb    = (bfu*)alloc(64ull * 1024 * 64 * 2);
  bfu* kb    = (bfu*)alloc(64ull * 1024 * 64 * 2);
  bfu* vb    = (bfu*)alloc(4096ull * 1024 * 2);
  bfu* vtb   = (bfu*)alloc(64ull * 1024 * 64 * 2);
  float* bqf = (float*)alloc(64ull * 1024 * 64 * 4);
  float* bkf = (float*)alloc(64ull * 1024 * 64 * 4);
  float* csum  = (float*)alloc(64ull * 8 * 64 * 4);
  float* browb = (float*)alloc(64ull * 1024 * 4);
  bfu* AB    = (bfu*)alloc(4096ull * 5120 * 2);       // [4096][5120] bf16: act | y

  // weights
  Ptr5 p5; p5.p[0] = Wq; p5.p[1] = Wk; p5.p[2] = Wv; p5.p[3] = WqB; p5.p[4] = WkB;
  wconv5<<<dim3(32, 32, 5), 256, 0, stream>>>(p5, wt5);
  wconv_t<1><<<dim3(256, 32), 256, 0, stream>>>(Wffin, wtfi, 1024, 8192, 1024, 0);
  wconv_t<0><<<dim3(32, 128), 256, 0, stream>>>(Wffout, wtfoc, 4096, 1024, 5120, 0);
  wconv_t<0><<<dim3(32, 32), 256, 0, stream>>>(Wo, wtfoc, 1024, 1024, 5120, 4096);
  rope_tab<<<128, 256, 0, stream>>>(cosb, sinb);
  rmsnorm_k<<<4096, 256, 0, stream>>>(h, inner);

  // fused 5-way projection + l2norm/rope epilogue: writes qb,kb,vb,bqf,bkf directly
  gemm256p<2><<<dim3(320), 512, 0, stream>>>(inner, wt5, nullptr, nullptr,
                                             qb, kb, vb, bqf, bkf, cosb, sinb,
                                             4096, 5120, 1024, 8, 5);

  vtrans<<<dim3(16, 64), 256, 0, stream>>>(vb, vtb);
  bk_chunksum<<<512, 64, 0, stream>>>(bkf, csum);
  brow_k<<<512, 64, 0, stream>>>(bqf, bkf, csum, browb);

  // flash writes y into AB cols 4096..
  flash_k<<<dim3(512), 256, 0, stream>>>(qb, kb, vtb, browb, l2ns, AB);

  // FF-in + silu fused -> AB cols 0..4095
  gemm256p<1><<<dim3(512), 512, 0, stream>>>(inner, wtfi, AB, bffin,
                                             nullptr, nullptr, nullptr, nullptr, nullptr,
                                             nullptr, nullptr,
                                             4096, 8192, 1024, 8, 8);

  // final merged: out = AB @ [Wffout|Wo]^T + bffout + bo + lam*h
  gemm128f<<<dim3(256), 256, 0, stream>>>(AB, wtfoc, out, bffout, bo, lam, h,
                                          4096, 1024, 5120, 8, 4);
}